// Round 5
// baseline (336.084 us; speedup 1.0000x reference)
//
#include <hip/hip_runtime.h>
#include <hip/hip_bf16.h>
#include <math.h>

// Modulated SIREN over 2-bit coordinate fields. Reference is a float32
// re-execution; network is chaotic (per-layer gain ~21-30x) so layers 1-2
// replicate the f32 rounding chain op-by-op (sequential fma, fbar value
// barriers against -ffp-contract re-fusion) with libm sinf. Layers 3-4
// tolerate ~1e-4 sin error -> 18-op inline sin30.
// Layer-4 GEMM (65536x256 @ 256x256) on MFMA via exact bf16 2-term split.
// Output stage: counting-sort points by c3 so each G3 row is read once
// (sequential 64 MB stream) instead of a 268 MB random gather.

typedef float  f32x4  __attribute__((ext_vector_type(4)));
typedef int    i32x4  __attribute__((ext_vector_type(4)));
typedef __bf16 bf16x8 __attribute__((ext_vector_type(8)));

__device__ __forceinline__ float fbar(float v) {
  asm volatile("" : "+v"(v));
  return v;
}

__device__ __forceinline__ unsigned short f2bf_rne(float x) {
  unsigned u = __float_as_uint(x);
  unsigned r = (u + 0x7fffu + ((u >> 16) & 1u)) >> 16;
  return (unsigned short)r;
}

// sin(30*x), |x| <~ 200. Double-single range reduction by 30/2pi, half-period
// fold via rint, deg-11 odd Taylor on [-0.25,0.25] rev, parity sign. ~6e-7 abs.
__device__ __forceinline__ float sin30(float x) {
  const float Ch = 4.774648189544678f;
  const float Cl = 1.0321218e-07f;
  float revh = x * Ch;
  fbar(revh);
  float e    = __builtin_fmaf(x, Ch, -revh);
  float revl = __builtin_fmaf(x, Cl, e);
  float k2   = __builtin_rintf(revh + revh);
  float g    = __builtin_fmaf(k2, -0.5f, revh) + revl;
  float g2 = g * g;
  float r = -15.0946f;
  r = __builtin_fmaf(r, g2, 42.0601f);
  r = __builtin_fmaf(r, g2, -76.70585f);
  r = __builtin_fmaf(r, g2, 81.6052492f);
  r = __builtin_fmaf(r, g2, -41.341702f);
  r = __builtin_fmaf(r, g2, 6.2831853f);
  float s = g * r;
  int ki = (int)k2;
  return __uint_as_float(__float_as_uint(s) ^ ((unsigned)(ki & 1) << 31));
}

__device__ __forceinline__ int coord_c3(int x, int y) {
  int c1 = ((x >> 8) & 3) * 64 + ((y >> 8) & 3) * 16 +
           (((y >> 6) & 3) * 4 + ((x >> 6) & 3));
  int i1 = ((y >> 4) & 3) * 4 + ((x >> 4) & 3);
  int i2 = ((y >> 2) & 3) * 4 + ((x >> 2) & 3);
  return (c1 * 16 + i1) * 16 + i2;
}

// M[j][i][d] = emb[j][i] @ modW[j]  (f32, sequential fma)
__global__ void k_mod(const float* __restrict__ emb, const float* __restrict__ modW,
                      float* __restrict__ Mf) {
  int ji = blockIdx.x;
  int j = ji >> 4, i = ji & 15, d = threadIdx.x;
  float acc = 0.0f;
#pragma unroll
  for (int e = 0; e < 16; ++e)
    acc = __builtin_fmaf(emb[j * 256 + i * 16 + e], modW[(j * 16 + e) * 256 + d], acc);
  Mf[ji * 256 + d] = acc;
}

// H1[c1][d] = sinf(30*( (lvx*W0[0]+lvy*W0[1]) + b0 + 30*M0[i0] ))  (libm)
__global__ void k_h1(const float* __restrict__ W0, const float* __restrict__ b0,
                     const float* __restrict__ Mf0, float* __restrict__ H1) {
  int c1 = blockIdx.x, d = threadIdx.x;
  float lvx = (float)((c1 >> 6) & 3), lvy = (float)((c1 >> 4) & 3);
  int i0 = c1 & 15;
  float t = fbar(lvx * W0[d]);
  t = __builtin_fmaf(lvy, W0[256 + d], t);
  t = fbar(t + b0[d]);
  float p = fbar(30.0f * Mf0[i0 * 256 + d]);
  float x = fbar(t + p);
  H1[c1 * 256 + d] = sinf(fbar(30.0f * x));
}

// H2[c1*16+i1][d] from H1[c1] @ Wh0 : K=256 sequential fma (libm sinf)
__global__ void k_h2(const float* __restrict__ H1, const float* __restrict__ Wh0,
                     const float* __restrict__ bh0, const float* __restrict__ Mf1,
                     float* __restrict__ H2) {
  __shared__ float xs[256];
  int c1 = blockIdx.x, d = threadIdx.x;
  xs[d] = H1[c1 * 256 + d];
  __syncthreads();
  float acc = 0.0f;
  for (int k = 0; k < 256; ++k)
    acc = __builtin_fmaf(xs[k], Wh0[k * 256 + d], acc);
  float t = fbar(acc + bh0[d]);
#pragma unroll 1
  for (int i1 = 0; i1 < 16; ++i1) {
    float p = fbar(30.0f * Mf1[i1 * 256 + d]);
    float x = fbar(t + p);
    H2[(c1 * 16 + i1) * 256 + d] = sinf(fbar(30.0f * x));
  }
}

// H3 rows as exact bf16 split Ah+Al. 1024 blocks x 4 c2-rows.
__global__ void k_h3ab(const float* __restrict__ H2, const float* __restrict__ W1,
                       const float* __restrict__ b1, const float* __restrict__ Mf2,
                       unsigned short* __restrict__ Ah, unsigned short* __restrict__ Al) {
  __shared__ float xs[4][256];
  int b = blockIdx.x, d = threadIdx.x;
#pragma unroll
  for (int r = 0; r < 4; ++r) xs[r][d] = H2[(b * 4 + r) * 256 + d];
  __syncthreads();
  float m2[16];
#pragma unroll
  for (int i = 0; i < 16; ++i) m2[i] = fbar(30.0f * Mf2[i * 256 + d]);
  float acc[4];
#pragma unroll
  for (int r = 0; r < 4; ++r) acc[r] = 0.0f;
  for (int k = 0; k < 256; ++k) {
    float w = W1[k * 256 + d];
#pragma unroll
    for (int r = 0; r < 4; ++r) acc[r] = __builtin_fmaf(xs[r][k], w, acc[r]);
  }
  float bias = b1[d];
#pragma unroll
  for (int r = 0; r < 4; ++r) {
    float t = fbar(acc[r] + bias);
    int c3base = (b * 4 + r) * 16;
#pragma unroll
    for (int i = 0; i < 16; ++i) {
      float x = fbar(t + m2[i]);
      float h = sin30(x);
      unsigned short hi = f2bf_rne(h);
      float hif = __uint_as_float((unsigned)hi << 16);
      unsigned short lo = f2bf_rne(h - hif);
      size_t o = (size_t)(c3base + i) * 256 + d;
      Ah[o] = hi;
      Al[o] = lo;
    }
  }
}

// B2T[col][k'] : [Bh ; Bl ; Bh] from W2[k][col], N-major (B^T).
__global__ void k_splitb(const float* __restrict__ W2, unsigned short* __restrict__ B2T) {
  int col = blockIdx.x, k = threadIdx.x;
  float w = W2[k * 256 + col];
  unsigned short hi = f2bf_rne(w);
  float hif = __uint_as_float((unsigned)hi << 16);
  unsigned short lo = f2bf_rne(w - hif);
  B2T[col * 768 + k] = hi;
  B2T[col * 768 + 256 + k] = lo;
  B2T[col * 768 + 512 + k] = hi;
}

// G3 = [Ah,Ah,Al] @ [Bh;Bl;Bh] + b2 : bf16 MFMA GEMM, M=65536 N=256 K=768.
__global__ void __launch_bounds__(512, 1) k_gemm(
    const unsigned short* __restrict__ Ah, const unsigned short* __restrict__ Al,
    const unsigned short* __restrict__ B2T, const float* __restrict__ b2,
    float* __restrict__ G3) {
  __shared__ unsigned short As[128 * 40];
  __shared__ unsigned short Bs[256 * 40];
  const int t = threadIdx.x;
  const int lane = t & 63, wid = t >> 6;
  const int l15 = lane & 15, l4 = lane >> 4;
  const int wm = (wid >> 2) * 64;
  const int wn = (wid & 3) * 64;
  const size_t r0 = (size_t)blockIdx.x * 128;

  const int s_arow = t >> 2, s_apart = t & 3;
  const int s_bcol0 = t >> 2, s_bcol1 = 128 + (t >> 2), s_bpart = t & 3;

  f32x4 acc[4][4];
#pragma unroll
  for (int rf = 0; rf < 4; ++rf)
#pragma unroll
    for (int cf = 0; cf < 4; ++cf) acc[rf][cf] = (f32x4){0.f, 0.f, 0.f, 0.f};

  i32x4 ra, rb0, rb1;
  ra  = *(const i32x4*)(Ah + ((r0 + s_arow) << 8) + s_apart * 8);
  rb0 = *(const i32x4*)(B2T + s_bcol0 * 768 + s_bpart * 8);
  rb1 = *(const i32x4*)(B2T + s_bcol1 * 768 + s_bpart * 8);

#pragma unroll 1
  for (int c = 0; c < 24; ++c) {
    *(i32x4*)(As + s_arow * 40 + s_apart * 8) = ra;
    *(i32x4*)(Bs + s_bcol0 * 40 + s_bpart * 8) = rb0;
    *(i32x4*)(Bs + s_bcol1 * 40 + s_bpart * 8) = rb1;
    __syncthreads();
    if (c < 23) {
      int cn = c + 1;
      int kk = cn & 7;
      const unsigned short* asrc = (cn >= 16) ? Al : Ah;
      ra  = *(const i32x4*)(asrc + ((r0 + s_arow) << 8) + kk * 32 + s_apart * 8);
      rb0 = *(const i32x4*)(B2T + s_bcol0 * 768 + cn * 32 + s_bpart * 8);
      rb1 = *(const i32x4*)(B2T + s_bcol1 * 768 + cn * 32 + s_bpart * 8);
    }
    bf16x8 af[4], bfr[4];
#pragma unroll
    for (int rf = 0; rf < 4; ++rf)
      af[rf] = __builtin_bit_cast(
          bf16x8, *(const i32x4*)(As + (wm + rf * 16 + l15) * 40 + l4 * 8));
#pragma unroll
    for (int cf = 0; cf < 4; ++cf)
      bfr[cf] = __builtin_bit_cast(
          bf16x8, *(const i32x4*)(Bs + (wn + cf * 16 + l15) * 40 + l4 * 8));
#pragma unroll
    for (int rf = 0; rf < 4; ++rf)
#pragma unroll
      for (int cf = 0; cf < 4; ++cf)
        acc[rf][cf] = __builtin_amdgcn_mfma_f32_16x16x32_bf16(
            af[rf], bfr[cf], acc[rf][cf], 0, 0, 0);
    __syncthreads();
  }

#pragma unroll
  for (int cf = 0; cf < 4; ++cf) {
    float bias = b2[wn + cf * 16 + l15];
#pragma unroll
    for (int rf = 0; rf < 4; ++rf) {
      size_t rbase = r0 + wm + rf * 16 + l4 * 4;
#pragma unroll
      for (int j = 0; j < 4; ++j)
        G3[(rbase + j) * 256 + wn + cf * 16 + l15] = acc[rf][cf][j] + bias;
    }
  }
}

// ---------------- counting sort of points by c3 ----------------

__global__ void k_zero(int* __restrict__ hist) {
  hist[blockIdx.x * 256 + threadIdx.x] = 0;
}

__global__ void k_hist(const int* __restrict__ coords, int* __restrict__ hist, int N) {
  int n = blockIdx.x * blockDim.x + threadIdx.x;
  if (n < N)
    atomicAdd(&hist[coord_c3(coords[2 * n], coords[2 * n + 1])], 1);
}

// single block, 1024 threads: exclusive scan of hist[65536] -> start, cursor
__global__ void __launch_bounds__(1024) k_scan(const int* __restrict__ hist,
                                               int* __restrict__ start,
                                               int* __restrict__ cursor) {
  __shared__ int ps[1024];
  int t = threadIdx.x, base = t * 64;
  int s = 0;
#pragma unroll 1
  for (int i = 0; i < 64; ++i) s += hist[base + i];
  ps[t] = s;
  __syncthreads();
  for (int off = 1; off < 1024; off <<= 1) {
    int v = 0;
    if (t >= off) v = ps[t - off];
    __syncthreads();
    ps[t] += v;
    __syncthreads();
  }
  int ex = (t == 0) ? 0 : ps[t - 1];
#pragma unroll 1
  for (int i = 0; i < 64; ++i) {
    start[base + i] = ex;
    cursor[base + i] = ex;
    ex += hist[base + i];
  }
  if (t == 1023) start[65536] = ex;
}

__global__ void k_scatter(const int* __restrict__ coords, int* __restrict__ cursor,
                          unsigned* __restrict__ sorted, int N) {
  int n = blockIdx.x * blockDim.x + threadIdx.x;
  if (n < N) {
    int x = coords[2 * n], y = coords[2 * n + 1];
    int c3 = coord_c3(x, y);
    int i3 = (y & 3) * 4 + (x & 3);
    int pos = atomicAdd(&cursor[c3], 1);
    sorted[pos] = ((unsigned)n << 4) | (unsigned)i3;
  }
}

// Sorted output: one 16-lane group per c3; G3 row in registers (read once),
// Mf3 in LDS. Per-point math/ordering identical to the round-4 k_out.
__global__ void __launch_bounds__(256) k_out2(
    const float* __restrict__ G3, const float* __restrict__ Mf3,
    const unsigned* __restrict__ sorted, const int* __restrict__ start,
    const float* __restrict__ Wl, const float* __restrict__ bl,
    float* __restrict__ out) {
  __shared__ float ms[16 * 256];
  int t = threadIdx.x;
#pragma unroll
  for (int i = 0; i < 4; ++i)
    *(float4*)(ms + (t + i * 256) * 4) = *(const float4*)(Mf3 + (t + i * 256) * 4);
  __syncthreads();

  int l = t & 15;
  int c3 = blockIdx.x * 16 + (t >> 4);
  float wl[4][4][3];
#pragma unroll
  for (int j = 0; j < 4; ++j)
#pragma unroll
    for (int k = 0; k < 4; ++k) {
      int d = j * 64 + l * 4 + k;
      wl[j][k][0] = Wl[d * 3 + 0];
      wl[j][k][1] = Wl[d * 3 + 1];
      wl[j][k][2] = Wl[d * 3 + 2];
    }
  float blv0 = bl[0], blv1 = bl[1], blv2 = bl[2];

  float gv[4][4];
  const float* gp = G3 + (size_t)c3 * 256 + l * 4;
#pragma unroll
  for (int j = 0; j < 4; ++j) {
    float4 g = *(const float4*)(gp + j * 64);
    gv[j][0] = g.x; gv[j][1] = g.y; gv[j][2] = g.z; gv[j][3] = g.w;
  }

  int s = start[c3], e = start[c3 + 1];
#pragma unroll 1
  for (int p = s; p < e; ++p) {
    unsigned ev = sorted[p];
    int n = (int)(ev >> 4);
    int i3 = (int)(ev & 15u);
    const float* mp = ms + i3 * 256 + l * 4;
    float p0 = 0.f, p1 = 0.f, p2 = 0.f;
#pragma unroll
    for (int j = 0; j < 4; ++j) {
      float4 m = *(const float4*)(mp + j * 64);
      float mv[4] = {m.x, m.y, m.z, m.w};
#pragma unroll
      for (int k = 0; k < 4; ++k) {
        float pm = fbar(30.0f * mv[k]);
        float xv = fbar(gv[j][k] + pm);
        float h = sin30(xv);
        p0 = __builtin_fmaf(h, wl[j][k][0], p0);
        p1 = __builtin_fmaf(h, wl[j][k][1], p1);
        p2 = __builtin_fmaf(h, wl[j][k][2], p2);
      }
    }
#pragma unroll
    for (int off = 1; off < 16; off <<= 1) {
      p0 += __shfl_xor(p0, off);
      p1 += __shfl_xor(p1, off);
      p2 += __shfl_xor(p2, off);
    }
    if (l == 0) {
      out[n * 3 + 0] = p0 + blv0;
      out[n * 3 + 1] = p1 + blv1;
      out[n * 3 + 2] = p2 + blv2;
    }
  }
}

// -------- fallback (ws too small): exact-f32 direct, block per point --------
__global__ void k_direct(const int* __restrict__ coords, const float* __restrict__ W0,
                         const float* __restrict__ b0, const float* __restrict__ Wh,
                         const float* __restrict__ bh, const float* __restrict__ emb,
                         const float* __restrict__ modW, const float* __restrict__ Wl,
                         const float* __restrict__ bl, float* __restrict__ out) {
  __shared__ float xs[256];
  __shared__ float red[256];
  int n = blockIdx.x, d = threadIdx.x;
  int x = coords[2 * n], y = coords[2 * n + 1];
  float lvx = (float)((x >> 8) & 3), lvy = (float)((y >> 8) & 3);
  int idx[4];
  idx[0] = ((y >> 6) & 3) * 4 + ((x >> 6) & 3);
  idx[1] = ((y >> 4) & 3) * 4 + ((x >> 4) & 3);
  idx[2] = ((y >> 2) & 3) * 4 + ((x >> 2) & 3);
  idx[3] = (y & 3) * 4 + (x & 3);
  float m = 0.0f;
#pragma unroll
  for (int e = 0; e < 16; ++e)
    m = __builtin_fmaf(emb[idx[0] * 16 + e], modW[e * 256 + d], m);
  float t = fbar(lvx * W0[d]);
  t = __builtin_fmaf(lvy, W0[256 + d], t);
  t = fbar(t + b0[d]);
  float p = fbar(30.0f * m);
  float xv = fbar(t + p);
  xs[d] = sinf(fbar(30.0f * xv));
  __syncthreads();
  for (int j = 0; j < 3; ++j) {
    float acc = 0.0f;
    for (int k = 0; k < 256; ++k)
      acc = __builtin_fmaf(xs[k], Wh[j * 65536 + k * 256 + d], acc);
    float tt = fbar(acc + bh[j * 256 + d]);
    m = 0.0f;
#pragma unroll
    for (int e = 0; e < 16; ++e)
      m = __builtin_fmaf(emb[(j + 1) * 256 + idx[j + 1] * 16 + e],
                         modW[((j + 1) * 16 + e) * 256 + d], m);
    p = fbar(30.0f * m);
    xv = fbar(tt + p);
    float h = sinf(fbar(30.0f * xv));
    __syncthreads();
    xs[d] = h;
    __syncthreads();
  }
  for (int q = 0; q < 3; ++q) {
    red[d] = xs[d] * Wl[d * 3 + q];
    __syncthreads();
    for (int s = 128; s > 0; s >>= 1) {
      if (d < s) red[d] += red[d + s];
      __syncthreads();
    }
    if (d == 0) out[n * 3 + q] = red[0] + bl[q];
    __syncthreads();
  }
}

// -------------------- launch --------------------
extern "C" void kernel_launch(void* const* d_in, const int* in_sizes, int n_in,
                              void* d_out, int out_size, void* d_ws, size_t ws_size,
                              hipStream_t stream) {
  const int*   coords = (const int*)d_in[0];
  const float* W0   = (const float*)d_in[1];
  const float* b0   = (const float*)d_in[2];
  const float* Wh   = (const float*)d_in[3];
  const float* bh   = (const float*)d_in[4];
  const float* emb  = (const float*)d_in[5];
  const float* modW = (const float*)d_in[6];
  const float* Wl   = (const float*)d_in[7];
  const float* bl   = (const float*)d_in[8];
  float* out = (float*)d_out;
  const int N = in_sizes[0] / 2;

  // layout: Mf | B2T | Ah | Al | G3(overlays H1,H2) | hist | start | cursor | sorted
  const size_t OFF_MF     = 0;          //  65536
  const size_t OFF_B2T    = 65536;      //  393216
  const size_t OFF_AH     = 458752;     //  33554432
  const size_t OFF_AL     = 34013184;   //  33554432
  const size_t OFF_G3     = 67567616;   //  67108864
  const size_t OFF_H1     = 67567616;   //  262144
  const size_t OFF_H2     = 67829760;   //  4194304
  const size_t OFF_HIST   = 134676480;  //  262144
  const size_t OFF_START  = 134938624;  //  262148
  const size_t OFF_CURSOR = 135200772;  //  262144
  const size_t OFF_SORTED = 135462916;  //  1048576
  const size_t NEED       = 136511492;

  if (ws_size >= NEED) {
    char* ws = (char*)d_ws;
    float*          Mf     = (float*)(ws + OFF_MF);
    unsigned short* B2T    = (unsigned short*)(ws + OFF_B2T);
    unsigned short* Ahp    = (unsigned short*)(ws + OFF_AH);
    unsigned short* Alp    = (unsigned short*)(ws + OFF_AL);
    float*          G3     = (float*)(ws + OFF_G3);
    float*          H1     = (float*)(ws + OFF_H1);
    float*          H2     = (float*)(ws + OFF_H2);
    int*            hist   = (int*)(ws + OFF_HIST);
    int*            startA = (int*)(ws + OFF_START);
    int*            cursor = (int*)(ws + OFF_CURSOR);
    unsigned*       sorted = (unsigned*)(ws + OFF_SORTED);

    // sort pipeline (independent of the math pipeline until k_out2)
    k_zero<<<256, 256, 0, stream>>>(hist);
    k_hist<<<1024, 256, 0, stream>>>(coords, hist, N);
    k_scan<<<1, 1024, 0, stream>>>(hist, startA, cursor);
    k_scatter<<<1024, 256, 0, stream>>>(coords, cursor, sorted, N);

    k_mod<<<64, 256, 0, stream>>>(emb, modW, Mf);
    k_splitb<<<256, 256, 0, stream>>>(Wh + 131072, B2T);
    k_h1<<<256, 256, 0, stream>>>(W0, b0, Mf, H1);
    k_h2<<<256, 256, 0, stream>>>(H1, Wh, bh, Mf + 4096, H2);
    k_h3ab<<<1024, 256, 0, stream>>>(H2, Wh + 65536, bh + 256, Mf + 8192, Ahp, Alp);
    k_gemm<<<512, 512, 0, stream>>>(Ahp, Alp, B2T, bh + 512, G3);
    k_out2<<<4096, 256, 0, stream>>>(G3, Mf + 12288, sorted, startA, Wl, bl, out);
  } else {
    k_direct<<<N, 256, 0, stream>>>(coords, W0, b0, Wh, bh, emb, modW, Wl, bl, out);
  }
}

// Round 6
// 205.592 us; speedup vs baseline: 1.6347x; 1.6347x over previous
//
#include <hip/hip_runtime.h>
#include <hip/hip_bf16.h>
#include <math.h>

// Modulated SIREN over 2-bit coordinate fields. Reference is a float32
// re-execution; network is chaotic (per-layer gain ~21-30x) so layers 1-2
// replicate the f32 rounding chain op-by-op (sequential fma, fbar value
// barriers against -ffp-contract re-fusion) with libm sinf. Layers 3-4
// tolerate ~1e-4 sin error -> 18-op inline sin30.
// Layer-4 GEMM (65536x256 @ 256x256) on MFMA via exact bf16 2-term split.
// Output stage: counting-sort points by c3 so each G3 row is read once.
// Scan is a 3-level parallel scan (single-block scan was 138 us serial).

typedef float  f32x4  __attribute__((ext_vector_type(4)));
typedef int    i32x4  __attribute__((ext_vector_type(4)));
typedef __bf16 bf16x8 __attribute__((ext_vector_type(8)));

__device__ __forceinline__ float fbar(float v) {
  asm volatile("" : "+v"(v));
  return v;
}

__device__ __forceinline__ unsigned short f2bf_rne(float x) {
  unsigned u = __float_as_uint(x);
  unsigned r = (u + 0x7fffu + ((u >> 16) & 1u)) >> 16;
  return (unsigned short)r;
}

// sin(30*x), |x| <~ 200. Double-single range reduction by 30/2pi, half-period
// fold via rint, deg-11 odd Taylor on [-0.25,0.25] rev, parity sign. ~6e-7 abs.
__device__ __forceinline__ float sin30(float x) {
  const float Ch = 4.774648189544678f;
  const float Cl = 1.0321218e-07f;
  float revh = x * Ch;
  fbar(revh);
  float e    = __builtin_fmaf(x, Ch, -revh);
  float revl = __builtin_fmaf(x, Cl, e);
  float k2   = __builtin_rintf(revh + revh);
  float g    = __builtin_fmaf(k2, -0.5f, revh) + revl;
  float g2 = g * g;
  float r = -15.0946f;
  r = __builtin_fmaf(r, g2, 42.0601f);
  r = __builtin_fmaf(r, g2, -76.70585f);
  r = __builtin_fmaf(r, g2, 81.6052492f);
  r = __builtin_fmaf(r, g2, -41.341702f);
  r = __builtin_fmaf(r, g2, 6.2831853f);
  float s = g * r;
  int ki = (int)k2;
  return __uint_as_float(__float_as_uint(s) ^ ((unsigned)(ki & 1) << 31));
}

__device__ __forceinline__ int coord_c3(int x, int y) {
  int c1 = ((x >> 8) & 3) * 64 + ((y >> 8) & 3) * 16 +
           (((y >> 6) & 3) * 4 + ((x >> 6) & 3));
  int i1 = ((y >> 4) & 3) * 4 + ((x >> 4) & 3);
  int i2 = ((y >> 2) & 3) * 4 + ((x >> 2) & 3);
  return (c1 * 16 + i1) * 16 + i2;
}

// M[j][i][d] = emb[j][i] @ modW[j]  (f32, sequential fma)
__global__ void k_mod(const float* __restrict__ emb, const float* __restrict__ modW,
                      float* __restrict__ Mf) {
  int ji = blockIdx.x;
  int j = ji >> 4, i = ji & 15, d = threadIdx.x;
  float acc = 0.0f;
#pragma unroll
  for (int e = 0; e < 16; ++e)
    acc = __builtin_fmaf(emb[j * 256 + i * 16 + e], modW[(j * 16 + e) * 256 + d], acc);
  Mf[ji * 256 + d] = acc;
}

// H1[c1][d] = sinf(30*( (lvx*W0[0]+lvy*W0[1]) + b0 + 30*M0[i0] ))  (libm)
__global__ void k_h1(const float* __restrict__ W0, const float* __restrict__ b0,
                     const float* __restrict__ Mf0, float* __restrict__ H1) {
  int c1 = blockIdx.x, d = threadIdx.x;
  float lvx = (float)((c1 >> 6) & 3), lvy = (float)((c1 >> 4) & 3);
  int i0 = c1 & 15;
  float t = fbar(lvx * W0[d]);
  t = __builtin_fmaf(lvy, W0[256 + d], t);
  t = fbar(t + b0[d]);
  float p = fbar(30.0f * Mf0[i0 * 256 + d]);
  float x = fbar(t + p);
  H1[c1 * 256 + d] = sinf(fbar(30.0f * x));
}

// H2[c1*16+i1][d] from H1[c1] @ Wh0 : K=256 sequential fma (libm sinf)
__global__ void k_h2(const float* __restrict__ H1, const float* __restrict__ Wh0,
                     const float* __restrict__ bh0, const float* __restrict__ Mf1,
                     float* __restrict__ H2) {
  __shared__ float xs[256];
  int c1 = blockIdx.x, d = threadIdx.x;
  xs[d] = H1[c1 * 256 + d];
  __syncthreads();
  float acc = 0.0f;
  for (int k = 0; k < 256; ++k)
    acc = __builtin_fmaf(xs[k], Wh0[k * 256 + d], acc);
  float t = fbar(acc + bh0[d]);
#pragma unroll 1
  for (int i1 = 0; i1 < 16; ++i1) {
    float p = fbar(30.0f * Mf1[i1 * 256 + d]);
    float x = fbar(t + p);
    H2[(c1 * 16 + i1) * 256 + d] = sinf(fbar(30.0f * x));
  }
}

// H3 rows as exact bf16 split Ah+Al. 1024 blocks x 4 c2-rows.
__global__ void k_h3ab(const float* __restrict__ H2, const float* __restrict__ W1,
                       const float* __restrict__ b1, const float* __restrict__ Mf2,
                       unsigned short* __restrict__ Ah, unsigned short* __restrict__ Al) {
  __shared__ float xs[4][256];
  int b = blockIdx.x, d = threadIdx.x;
#pragma unroll
  for (int r = 0; r < 4; ++r) xs[r][d] = H2[(b * 4 + r) * 256 + d];
  __syncthreads();
  float m2[16];
#pragma unroll
  for (int i = 0; i < 16; ++i) m2[i] = fbar(30.0f * Mf2[i * 256 + d]);
  float acc[4];
#pragma unroll
  for (int r = 0; r < 4; ++r) acc[r] = 0.0f;
  for (int k = 0; k < 256; ++k) {
    float w = W1[k * 256 + d];
#pragma unroll
    for (int r = 0; r < 4; ++r) acc[r] = __builtin_fmaf(xs[r][k], w, acc[r]);
  }
  float bias = b1[d];
#pragma unroll
  for (int r = 0; r < 4; ++r) {
    float t = fbar(acc[r] + bias);
    int c3base = (b * 4 + r) * 16;
#pragma unroll
    for (int i = 0; i < 16; ++i) {
      float x = fbar(t + m2[i]);
      float h = sin30(x);
      unsigned short hi = f2bf_rne(h);
      float hif = __uint_as_float((unsigned)hi << 16);
      unsigned short lo = f2bf_rne(h - hif);
      size_t o = (size_t)(c3base + i) * 256 + d;
      Ah[o] = hi;
      Al[o] = lo;
    }
  }
}

// B2T[col][k'] : [Bh ; Bl ; Bh] from W2[k][col], N-major (B^T).
__global__ void k_splitb(const float* __restrict__ W2, unsigned short* __restrict__ B2T) {
  int col = blockIdx.x, k = threadIdx.x;
  float w = W2[k * 256 + col];
  unsigned short hi = f2bf_rne(w);
  float hif = __uint_as_float((unsigned)hi << 16);
  unsigned short lo = f2bf_rne(w - hif);
  B2T[col * 768 + k] = hi;
  B2T[col * 768 + 256 + k] = lo;
  B2T[col * 768 + 512 + k] = hi;
}

// G3 = [Ah,Ah,Al] @ [Bh;Bl;Bh] + b2 : bf16 MFMA GEMM, M=65536 N=256 K=768.
__global__ void __launch_bounds__(512, 1) k_gemm(
    const unsigned short* __restrict__ Ah, const unsigned short* __restrict__ Al,
    const unsigned short* __restrict__ B2T, const float* __restrict__ b2,
    float* __restrict__ G3) {
  __shared__ unsigned short As[128 * 40];
  __shared__ unsigned short Bs[256 * 40];
  const int t = threadIdx.x;
  const int lane = t & 63, wid = t >> 6;
  const int l15 = lane & 15, l4 = lane >> 4;
  const int wm = (wid >> 2) * 64;
  const int wn = (wid & 3) * 64;
  const size_t r0 = (size_t)blockIdx.x * 128;

  const int s_arow = t >> 2, s_apart = t & 3;
  const int s_bcol0 = t >> 2, s_bcol1 = 128 + (t >> 2), s_bpart = t & 3;

  f32x4 acc[4][4];
#pragma unroll
  for (int rf = 0; rf < 4; ++rf)
#pragma unroll
    for (int cf = 0; cf < 4; ++cf) acc[rf][cf] = (f32x4){0.f, 0.f, 0.f, 0.f};

  i32x4 ra, rb0, rb1;
  ra  = *(const i32x4*)(Ah + ((r0 + s_arow) << 8) + s_apart * 8);
  rb0 = *(const i32x4*)(B2T + s_bcol0 * 768 + s_bpart * 8);
  rb1 = *(const i32x4*)(B2T + s_bcol1 * 768 + s_bpart * 8);

#pragma unroll 1
  for (int c = 0; c < 24; ++c) {
    *(i32x4*)(As + s_arow * 40 + s_apart * 8) = ra;
    *(i32x4*)(Bs + s_bcol0 * 40 + s_bpart * 8) = rb0;
    *(i32x4*)(Bs + s_bcol1 * 40 + s_bpart * 8) = rb1;
    __syncthreads();
    if (c < 23) {
      int cn = c + 1;
      int kk = cn & 7;
      const unsigned short* asrc = (cn >= 16) ? Al : Ah;
      ra  = *(const i32x4*)(asrc + ((r0 + s_arow) << 8) + kk * 32 + s_apart * 8);
      rb0 = *(const i32x4*)(B2T + s_bcol0 * 768 + cn * 32 + s_bpart * 8);
      rb1 = *(const i32x4*)(B2T + s_bcol1 * 768 + cn * 32 + s_bpart * 8);
    }
    bf16x8 af[4], bfr[4];
#pragma unroll
    for (int rf = 0; rf < 4; ++rf)
      af[rf] = __builtin_bit_cast(
          bf16x8, *(const i32x4*)(As + (wm + rf * 16 + l15) * 40 + l4 * 8));
#pragma unroll
    for (int cf = 0; cf < 4; ++cf)
      bfr[cf] = __builtin_bit_cast(
          bf16x8, *(const i32x4*)(Bs + (wn + cf * 16 + l15) * 40 + l4 * 8));
#pragma unroll
    for (int rf = 0; rf < 4; ++rf)
#pragma unroll
      for (int cf = 0; cf < 4; ++cf)
        acc[rf][cf] = __builtin_amdgcn_mfma_f32_16x16x32_bf16(
            af[rf], bfr[cf], acc[rf][cf], 0, 0, 0);
    __syncthreads();
  }

#pragma unroll
  for (int cf = 0; cf < 4; ++cf) {
    float bias = b2[wn + cf * 16 + l15];
#pragma unroll
    for (int rf = 0; rf < 4; ++rf) {
      size_t rbase = r0 + wm + rf * 16 + l4 * 4;
#pragma unroll
      for (int j = 0; j < 4; ++j)
        G3[(rbase + j) * 256 + wn + cf * 16 + l15] = acc[rf][cf][j] + bias;
    }
  }
}

// ---------------- counting sort of points by c3 ----------------

__global__ void k_zero(int* __restrict__ hist) {
  hist[blockIdx.x * 256 + threadIdx.x] = 0;
}

__global__ void k_hist(const int* __restrict__ coords, int* __restrict__ hist, int N) {
  int n = blockIdx.x * blockDim.x + threadIdx.x;
  if (n < N)
    atomicAdd(&hist[coord_c3(coords[2 * n], coords[2 * n + 1])], 1);
}

// 3-level parallel scan of hist[65536]:
// scan1: per-block (256 blocks x 256 thr) inclusive scan -> scani, bsum[256]
__global__ void k_scan1(const int* __restrict__ hist, int* __restrict__ scani,
                        int* __restrict__ bsum) {
  __shared__ int ps[256];
  int b = blockIdx.x, t = threadIdx.x, g = b * 256 + t;
  int h = hist[g];
  ps[t] = h;
  __syncthreads();
#pragma unroll
  for (int off = 1; off < 256; off <<= 1) {
    int v = (t >= off) ? ps[t - off] : 0;
    __syncthreads();
    ps[t] += v;
    __syncthreads();
  }
  scani[g] = ps[t];
  if (t == 255) bsum[b] = ps[255];
}

// scan2: single block, exclusive scan of bsum[256] -> boff[256]
__global__ void k_scan2(const int* __restrict__ bsum, int* __restrict__ boff) {
  __shared__ int ps[256];
  int t = threadIdx.x;
  int v0 = bsum[t];
  ps[t] = v0;
  __syncthreads();
#pragma unroll
  for (int off = 1; off < 256; off <<= 1) {
    int v = (t >= off) ? ps[t - off] : 0;
    __syncthreads();
    ps[t] += v;
    __syncthreads();
  }
  boff[t] = ps[t] - v0;
}

// scan3: start/cursor = exclusive global scan; start[65536] = N
__global__ void k_scan3(const int* __restrict__ hist, const int* __restrict__ scani,
                        const int* __restrict__ boff, int* __restrict__ start,
                        int* __restrict__ cursor) {
  int b = blockIdx.x, t = threadIdx.x, g = b * 256 + t;
  int h = hist[g];
  int ex = boff[b] + scani[g] - h;
  start[g] = ex;
  cursor[g] = ex;
  if (g == 65535) start[65536] = ex + h;
}

__global__ void k_scatter(const int* __restrict__ coords, int* __restrict__ cursor,
                          unsigned* __restrict__ sorted, int N) {
  int n = blockIdx.x * blockDim.x + threadIdx.x;
  if (n < N) {
    int x = coords[2 * n], y = coords[2 * n + 1];
    int c3 = coord_c3(x, y);
    int i3 = (y & 3) * 4 + (x & 3);
    int pos = atomicAdd(&cursor[c3], 1);
    sorted[pos] = ((unsigned)n << 4) | (unsigned)i3;
  }
}

// Sorted output: one 16-lane group per c3; G3 row in registers (read once),
// Mf3 in LDS. Per-point math/ordering identical to the round-4 k_out.
__global__ void __launch_bounds__(256) k_out2(
    const float* __restrict__ G3, const float* __restrict__ Mf3,
    const unsigned* __restrict__ sorted, const int* __restrict__ start,
    const float* __restrict__ Wl, const float* __restrict__ bl,
    float* __restrict__ out) {
  __shared__ float ms[16 * 256];
  int t = threadIdx.x;
#pragma unroll
  for (int i = 0; i < 4; ++i)
    *(float4*)(ms + (t + i * 256) * 4) = *(const float4*)(Mf3 + (t + i * 256) * 4);
  __syncthreads();

  int l = t & 15;
  int c3 = blockIdx.x * 16 + (t >> 4);
  float wl[4][4][3];
#pragma unroll
  for (int j = 0; j < 4; ++j)
#pragma unroll
    for (int k = 0; k < 4; ++k) {
      int d = j * 64 + l * 4 + k;
      wl[j][k][0] = Wl[d * 3 + 0];
      wl[j][k][1] = Wl[d * 3 + 1];
      wl[j][k][2] = Wl[d * 3 + 2];
    }
  float blv0 = bl[0], blv1 = bl[1], blv2 = bl[2];

  float gv[4][4];
  const float* gp = G3 + (size_t)c3 * 256 + l * 4;
#pragma unroll
  for (int j = 0; j < 4; ++j) {
    float4 g = *(const float4*)(gp + j * 64);
    gv[j][0] = g.x; gv[j][1] = g.y; gv[j][2] = g.z; gv[j][3] = g.w;
  }

  int s = start[c3], e = start[c3 + 1];
#pragma unroll 1
  for (int p = s; p < e; ++p) {
    unsigned ev = sorted[p];
    int n = (int)(ev >> 4);
    int i3 = (int)(ev & 15u);
    const float* mp = ms + i3 * 256 + l * 4;
    float p0 = 0.f, p1 = 0.f, p2 = 0.f;
#pragma unroll
    for (int j = 0; j < 4; ++j) {
      float4 m = *(const float4*)(mp + j * 64);
      float mv[4] = {m.x, m.y, m.z, m.w};
#pragma unroll
      for (int k = 0; k < 4; ++k) {
        float pm = fbar(30.0f * mv[k]);
        float xv = fbar(gv[j][k] + pm);
        float h = sin30(xv);
        p0 = __builtin_fmaf(h, wl[j][k][0], p0);
        p1 = __builtin_fmaf(h, wl[j][k][1], p1);
        p2 = __builtin_fmaf(h, wl[j][k][2], p2);
      }
    }
#pragma unroll
    for (int off = 1; off < 16; off <<= 1) {
      p0 += __shfl_xor(p0, off);
      p1 += __shfl_xor(p1, off);
      p2 += __shfl_xor(p2, off);
    }
    if (l == 0) {
      out[n * 3 + 0] = p0 + blv0;
      out[n * 3 + 1] = p1 + blv1;
      out[n * 3 + 2] = p2 + blv2;
    }
  }
}

// -------- fallback (ws too small): exact-f32 direct, block per point --------
__global__ void k_direct(const int* __restrict__ coords, const float* __restrict__ W0,
                         const float* __restrict__ b0, const float* __restrict__ Wh,
                         const float* __restrict__ bh, const float* __restrict__ emb,
                         const float* __restrict__ modW, const float* __restrict__ Wl,
                         const float* __restrict__ bl, float* __restrict__ out) {
  __shared__ float xs[256];
  __shared__ float red[256];
  int n = blockIdx.x, d = threadIdx.x;
  int x = coords[2 * n], y = coords[2 * n + 1];
  float lvx = (float)((x >> 8) & 3), lvy = (float)((y >> 8) & 3);
  int idx[4];
  idx[0] = ((y >> 6) & 3) * 4 + ((x >> 6) & 3);
  idx[1] = ((y >> 4) & 3) * 4 + ((x >> 4) & 3);
  idx[2] = ((y >> 2) & 3) * 4 + ((x >> 2) & 3);
  idx[3] = (y & 3) * 4 + (x & 3);
  float m = 0.0f;
#pragma unroll
  for (int e = 0; e < 16; ++e)
    m = __builtin_fmaf(emb[idx[0] * 16 + e], modW[e * 256 + d], m);
  float t = fbar(lvx * W0[d]);
  t = __builtin_fmaf(lvy, W0[256 + d], t);
  t = fbar(t + b0[d]);
  float p = fbar(30.0f * m);
  float xv = fbar(t + p);
  xs[d] = sinf(fbar(30.0f * xv));
  __syncthreads();
  for (int j = 0; j < 3; ++j) {
    float acc = 0.0f;
    for (int k = 0; k < 256; ++k)
      acc = __builtin_fmaf(xs[k], Wh[j * 65536 + k * 256 + d], acc);
    float tt = fbar(acc + bh[j * 256 + d]);
    m = 0.0f;
#pragma unroll
    for (int e = 0; e < 16; ++e)
      m = __builtin_fmaf(emb[(j + 1) * 256 + idx[j + 1] * 16 + e],
                         modW[((j + 1) * 16 + e) * 256 + d], m);
    p = fbar(30.0f * m);
    xv = fbar(tt + p);
    float h = sinf(fbar(30.0f * xv));
    __syncthreads();
    xs[d] = h;
    __syncthreads();
  }
  for (int q = 0; q < 3; ++q) {
    red[d] = xs[d] * Wl[d * 3 + q];
    __syncthreads();
    for (int s = 128; s > 0; s >>= 1) {
      if (d < s) red[d] += red[d + s];
      __syncthreads();
    }
    if (d == 0) out[n * 3 + q] = red[0] + bl[q];
    __syncthreads();
  }
}

// -------------------- launch --------------------
extern "C" void kernel_launch(void* const* d_in, const int* in_sizes, int n_in,
                              void* d_out, int out_size, void* d_ws, size_t ws_size,
                              hipStream_t stream) {
  const int*   coords = (const int*)d_in[0];
  const float* W0   = (const float*)d_in[1];
  const float* b0   = (const float*)d_in[2];
  const float* Wh   = (const float*)d_in[3];
  const float* bh   = (const float*)d_in[4];
  const float* emb  = (const float*)d_in[5];
  const float* modW = (const float*)d_in[6];
  const float* Wl   = (const float*)d_in[7];
  const float* bl   = (const float*)d_in[8];
  float* out = (float*)d_out;
  const int N = in_sizes[0] / 2;

  // layout: Mf | B2T | Ah | Al | G3(overlays H1,H2) | hist | start | cursor |
  //         sorted | scani | bsum | boff
  const size_t OFF_MF     = 0;          //  65536
  const size_t OFF_B2T    = 65536;      //  393216
  const size_t OFF_AH     = 458752;     //  33554432
  const size_t OFF_AL     = 34013184;   //  33554432
  const size_t OFF_G3     = 67567616;   //  67108864
  const size_t OFF_H1     = 67567616;   //  262144
  const size_t OFF_H2     = 67829760;   //  4194304
  const size_t OFF_HIST   = 134676480;  //  262144
  const size_t OFF_START  = 134938624;  //  262148
  const size_t OFF_CURSOR = 135200772;  //  262144
  const size_t OFF_SORTED = 135462916;  //  1048576
  const size_t OFF_SCANI  = 136511492;  //  262144
  const size_t OFF_BSUM   = 136773636;  //  1024
  const size_t OFF_BOFF   = 136774660;  //  1024
  const size_t NEED       = 136775684;

  if (ws_size >= NEED) {
    char* ws = (char*)d_ws;
    float*          Mf     = (float*)(ws + OFF_MF);
    unsigned short* B2T    = (unsigned short*)(ws + OFF_B2T);
    unsigned short* Ahp    = (unsigned short*)(ws + OFF_AH);
    unsigned short* Alp    = (unsigned short*)(ws + OFF_AL);
    float*          G3     = (float*)(ws + OFF_G3);
    float*          H1     = (float*)(ws + OFF_H1);
    float*          H2     = (float*)(ws + OFF_H2);
    int*            hist   = (int*)(ws + OFF_HIST);
    int*            startA = (int*)(ws + OFF_START);
    int*            cursor = (int*)(ws + OFF_CURSOR);
    unsigned*       sorted = (unsigned*)(ws + OFF_SORTED);
    int*            scani  = (int*)(ws + OFF_SCANI);
    int*            bsum   = (int*)(ws + OFF_BSUM);
    int*            boff   = (int*)(ws + OFF_BOFF);

    // sort pipeline (independent of the math pipeline until k_out2)
    k_zero<<<256, 256, 0, stream>>>(hist);
    k_hist<<<1024, 256, 0, stream>>>(coords, hist, N);
    k_scan1<<<256, 256, 0, stream>>>(hist, scani, bsum);
    k_scan2<<<1, 256, 0, stream>>>(bsum, boff);
    k_scan3<<<256, 256, 0, stream>>>(hist, scani, boff, startA, cursor);
    k_scatter<<<1024, 256, 0, stream>>>(coords, cursor, sorted, N);

    k_mod<<<64, 256, 0, stream>>>(emb, modW, Mf);
    k_splitb<<<256, 256, 0, stream>>>(Wh + 131072, B2T);
    k_h1<<<256, 256, 0, stream>>>(W0, b0, Mf, H1);
    k_h2<<<256, 256, 0, stream>>>(H1, Wh, bh, Mf + 4096, H2);
    k_h3ab<<<1024, 256, 0, stream>>>(H2, Wh + 65536, bh + 256, Mf + 8192, Ahp, Alp);
    k_gemm<<<512, 512, 0, stream>>>(Ahp, Alp, B2T, bh + 512, G3);
    k_out2<<<4096, 256, 0, stream>>>(G3, Mf + 12288, sorted, startA, Wl, bl, out);
  } else {
    k_direct<<<N, 256, 0, stream>>>(coords, W0, b0, Wh, bh, emb, modW, Wl, bl, out);
  }
}

// Round 7
// 175.657 us; speedup vs baseline: 1.9133x; 1.1704x over previous
//
#include <hip/hip_runtime.h>
#include <hip/hip_bf16.h>
#include <math.h>

// Modulated SIREN over 2-bit coordinate fields. Reference is a float32
// re-execution; network is chaotic (per-layer gain ~21-30x) so layers 1-2
// replicate the f32 rounding chain op-by-op (sequential fma, fbar value
// barriers against -ffp-contract re-fusion) with libm sinf. Layers 3-4
// tolerate ~1e-3 output error -> inline sin30/sincos30 (double-single range
// reduction + Taylor polys).
// Layer-4 GEMM (65536x256 @ 256x256) on MFMA via exact bf16 2-term split.
// Output stage: counting-sort points by c3; per c3 compute sincos30(G3 row)
// ONCE, then per point h = sinA*cos(900m) + cosA*sin(900m) via 16x256 LDS
// tables (angle addition) -> 2 VALU/element instead of a full sine.

typedef float  f32x4  __attribute__((ext_vector_type(4)));
typedef int    i32x4  __attribute__((ext_vector_type(4)));
typedef __bf16 bf16x8 __attribute__((ext_vector_type(8)));

__device__ __forceinline__ float fbar(float v) {
  asm volatile("" : "+v"(v));
  return v;
}

__device__ __forceinline__ unsigned short f2bf_rne(float x) {
  unsigned u = __float_as_uint(x);
  unsigned r = (u + 0x7fffu + ((u >> 16) & 1u)) >> 16;
  return (unsigned short)r;
}

// sin(30*x), |x| <~ 200. Double-single range reduction by 30/2pi, half-period
// fold via rint, deg-11 odd Taylor on [-0.25,0.25] rev, parity sign. ~1e-6 abs.
__device__ __forceinline__ float sin30(float x) {
  const float Ch = 4.774648189544678f;
  const float Cl = 1.0321218e-07f;
  float revh = x * Ch;
  fbar(revh);
  float e    = __builtin_fmaf(x, Ch, -revh);
  float revl = __builtin_fmaf(x, Cl, e);
  float k2   = __builtin_rintf(revh + revh);
  float g    = __builtin_fmaf(k2, -0.5f, revh) + revl;
  float g2 = g * g;
  float r = -15.0946f;
  r = __builtin_fmaf(r, g2, 42.0601f);
  r = __builtin_fmaf(r, g2, -76.70585f);
  r = __builtin_fmaf(r, g2, 81.6052492f);
  r = __builtin_fmaf(r, g2, -41.341702f);
  r = __builtin_fmaf(r, g2, 6.2831853f);
  float s = g * r;
  int ki = (int)k2;
  return __uint_as_float(__float_as_uint(s) ^ ((unsigned)(ki & 1) << 31));
}

// sin(30*x) AND cos(30*x): shared range reduction, odd+even Taylor polys.
__device__ __forceinline__ void sincos30(float x, float* so, float* co) {
  const float Ch = 4.774648189544678f;
  const float Cl = 1.0321218e-07f;
  float revh = x * Ch;
  fbar(revh);
  float e    = __builtin_fmaf(x, Ch, -revh);
  float revl = __builtin_fmaf(x, Cl, e);
  float k2   = __builtin_rintf(revh + revh);
  float g    = __builtin_fmaf(k2, -0.5f, revh) + revl;
  float u = g * g;
  float sr = -15.0946f;
  sr = __builtin_fmaf(sr, u, 42.0601f);
  sr = __builtin_fmaf(sr, u, -76.70585f);
  sr = __builtin_fmaf(sr, u, 81.6052492f);
  sr = __builtin_fmaf(sr, u, -41.341702f);
  sr = __builtin_fmaf(sr, u, 6.2831853f);
  float s = g * sr;
  float cr = -26.4259f;
  cr = __builtin_fmaf(cr, u, 60.2446f);
  cr = __builtin_fmaf(cr, u, -85.4568f);
  cr = __builtin_fmaf(cr, u, 64.9393940f);
  cr = __builtin_fmaf(cr, u, -19.7392088f);
  float c = __builtin_fmaf(cr, u, 1.0f);
  int ki = (int)k2;
  unsigned sgn = ((unsigned)(ki & 1)) << 31;
  *so = __uint_as_float(__float_as_uint(s) ^ sgn);
  *co = __uint_as_float(__float_as_uint(c) ^ sgn);
}

__device__ __forceinline__ int coord_c3(int x, int y) {
  int c1 = ((x >> 8) & 3) * 64 + ((y >> 8) & 3) * 16 +
           (((y >> 6) & 3) * 4 + ((x >> 6) & 3));
  int i1 = ((y >> 4) & 3) * 4 + ((x >> 4) & 3);
  int i2 = ((y >> 2) & 3) * 4 + ((x >> 2) & 3);
  return (c1 * 16 + i1) * 16 + i2;
}

// M[j][i][d] = emb[j][i] @ modW[j]  (f32, sequential fma)
__global__ void k_mod(const float* __restrict__ emb, const float* __restrict__ modW,
                      float* __restrict__ Mf) {
  int ji = blockIdx.x;
  int j = ji >> 4, i = ji & 15, d = threadIdx.x;
  float acc = 0.0f;
#pragma unroll
  for (int e = 0; e < 16; ++e)
    acc = __builtin_fmaf(emb[j * 256 + i * 16 + e], modW[(j * 16 + e) * 256 + d], acc);
  Mf[ji * 256 + d] = acc;
}

// Tables for the output stage: angle of the i3 modulator, ref-faithful
// pm = fl(30*m); TC/TS = cos/sin(30*pm).
__global__ void k_tab(const float* __restrict__ Mf3, float* __restrict__ TC,
                      float* __restrict__ TS) {
  int i3 = blockIdx.x, d = threadIdx.x;
  float pm = fbar(30.0f * Mf3[i3 * 256 + d]);
  float s, c;
  sincos30(pm, &s, &c);
  TC[i3 * 256 + d] = c;
  TS[i3 * 256 + d] = s;
}

// H1[c1][d] = sinf(30*( (lvx*W0[0]+lvy*W0[1]) + b0 + 30*M0[i0] ))  (libm)
__global__ void k_h1(const float* __restrict__ W0, const float* __restrict__ b0,
                     const float* __restrict__ Mf0, float* __restrict__ H1) {
  int c1 = blockIdx.x, d = threadIdx.x;
  float lvx = (float)((c1 >> 6) & 3), lvy = (float)((c1 >> 4) & 3);
  int i0 = c1 & 15;
  float t = fbar(lvx * W0[d]);
  t = __builtin_fmaf(lvy, W0[256 + d], t);
  t = fbar(t + b0[d]);
  float p = fbar(30.0f * Mf0[i0 * 256 + d]);
  float x = fbar(t + p);
  H1[c1 * 256 + d] = sinf(fbar(30.0f * x));
}

// H2[c1*16+i1][d] from H1[c1] @ Wh0 : K=256 sequential fma (libm sinf)
__global__ void k_h2(const float* __restrict__ H1, const float* __restrict__ Wh0,
                     const float* __restrict__ bh0, const float* __restrict__ Mf1,
                     float* __restrict__ H2) {
  __shared__ float xs[256];
  int c1 = blockIdx.x, d = threadIdx.x;
  xs[d] = H1[c1 * 256 + d];
  __syncthreads();
  float acc = 0.0f;
  for (int k = 0; k < 256; ++k)
    acc = __builtin_fmaf(xs[k], Wh0[k * 256 + d], acc);
  float t = fbar(acc + bh0[d]);
#pragma unroll 1
  for (int i1 = 0; i1 < 16; ++i1) {
    float p = fbar(30.0f * Mf1[i1 * 256 + d]);
    float x = fbar(t + p);
    H2[(c1 * 16 + i1) * 256 + d] = sinf(fbar(30.0f * x));
  }
}

// H3 rows as exact bf16 split Ah+Al. 1024 blocks x 4 c2-rows.
__global__ void k_h3ab(const float* __restrict__ H2, const float* __restrict__ W1,
                       const float* __restrict__ b1, const float* __restrict__ Mf2,
                       unsigned short* __restrict__ Ah, unsigned short* __restrict__ Al) {
  __shared__ float xs[4][256];
  int b = blockIdx.x, d = threadIdx.x;
#pragma unroll
  for (int r = 0; r < 4; ++r) xs[r][d] = H2[(b * 4 + r) * 256 + d];
  __syncthreads();
  float m2[16];
#pragma unroll
  for (int i = 0; i < 16; ++i) m2[i] = fbar(30.0f * Mf2[i * 256 + d]);
  float acc[4];
#pragma unroll
  for (int r = 0; r < 4; ++r) acc[r] = 0.0f;
  for (int k = 0; k < 256; ++k) {
    float w = W1[k * 256 + d];
#pragma unroll
    for (int r = 0; r < 4; ++r) acc[r] = __builtin_fmaf(xs[r][k], w, acc[r]);
  }
  float bias = b1[d];
#pragma unroll
  for (int r = 0; r < 4; ++r) {
    float t = fbar(acc[r] + bias);
    int c3base = (b * 4 + r) * 16;
#pragma unroll
    for (int i = 0; i < 16; ++i) {
      float x = fbar(t + m2[i]);
      float h = sin30(x);
      unsigned short hi = f2bf_rne(h);
      float hif = __uint_as_float((unsigned)hi << 16);
      unsigned short lo = f2bf_rne(h - hif);
      size_t o = (size_t)(c3base + i) * 256 + d;
      Ah[o] = hi;
      Al[o] = lo;
    }
  }
}

// B2T[col][k'] : [Bh ; Bl ; Bh] from W2[k][col], N-major (B^T).
__global__ void k_splitb(const float* __restrict__ W2, unsigned short* __restrict__ B2T) {
  int col = blockIdx.x, k = threadIdx.x;
  float w = W2[k * 256 + col];
  unsigned short hi = f2bf_rne(w);
  float hif = __uint_as_float((unsigned)hi << 16);
  unsigned short lo = f2bf_rne(w - hif);
  B2T[col * 768 + k] = hi;
  B2T[col * 768 + 256 + k] = lo;
  B2T[col * 768 + 512 + k] = hi;
}

// G3 = [Ah,Ah,Al] @ [Bh;Bl;Bh] + b2 : bf16 MFMA GEMM, M=65536 N=256 K=768.
__global__ void __launch_bounds__(512, 1) k_gemm(
    const unsigned short* __restrict__ Ah, const unsigned short* __restrict__ Al,
    const unsigned short* __restrict__ B2T, const float* __restrict__ b2,
    float* __restrict__ G3) {
  __shared__ unsigned short As[128 * 40];
  __shared__ unsigned short Bs[256 * 40];
  const int t = threadIdx.x;
  const int lane = t & 63, wid = t >> 6;
  const int l15 = lane & 15, l4 = lane >> 4;
  const int wm = (wid >> 2) * 64;
  const int wn = (wid & 3) * 64;
  const size_t r0 = (size_t)blockIdx.x * 128;

  const int s_arow = t >> 2, s_apart = t & 3;
  const int s_bcol0 = t >> 2, s_bcol1 = 128 + (t >> 2), s_bpart = t & 3;

  f32x4 acc[4][4];
#pragma unroll
  for (int rf = 0; rf < 4; ++rf)
#pragma unroll
    for (int cf = 0; cf < 4; ++cf) acc[rf][cf] = (f32x4){0.f, 0.f, 0.f, 0.f};

  i32x4 ra, rb0, rb1;
  ra  = *(const i32x4*)(Ah + ((r0 + s_arow) << 8) + s_apart * 8);
  rb0 = *(const i32x4*)(B2T + s_bcol0 * 768 + s_bpart * 8);
  rb1 = *(const i32x4*)(B2T + s_bcol1 * 768 + s_bpart * 8);

#pragma unroll 1
  for (int c = 0; c < 24; ++c) {
    *(i32x4*)(As + s_arow * 40 + s_apart * 8) = ra;
    *(i32x4*)(Bs + s_bcol0 * 40 + s_bpart * 8) = rb0;
    *(i32x4*)(Bs + s_bcol1 * 40 + s_bpart * 8) = rb1;
    __syncthreads();
    if (c < 23) {
      int cn = c + 1;
      int kk = cn & 7;
      const unsigned short* asrc = (cn >= 16) ? Al : Ah;
      ra  = *(const i32x4*)(asrc + ((r0 + s_arow) << 8) + kk * 32 + s_apart * 8);
      rb0 = *(const i32x4*)(B2T + s_bcol0 * 768 + cn * 32 + s_bpart * 8);
      rb1 = *(const i32x4*)(B2T + s_bcol1 * 768 + cn * 32 + s_bpart * 8);
    }
    bf16x8 af[4], bfr[4];
#pragma unroll
    for (int rf = 0; rf < 4; ++rf)
      af[rf] = __builtin_bit_cast(
          bf16x8, *(const i32x4*)(As + (wm + rf * 16 + l15) * 40 + l4 * 8));
#pragma unroll
    for (int cf = 0; cf < 4; ++cf)
      bfr[cf] = __builtin_bit_cast(
          bf16x8, *(const i32x4*)(Bs + (wn + cf * 16 + l15) * 40 + l4 * 8));
#pragma unroll
    for (int rf = 0; rf < 4; ++rf)
#pragma unroll
      for (int cf = 0; cf < 4; ++cf)
        acc[rf][cf] = __builtin_amdgcn_mfma_f32_16x16x32_bf16(
            af[rf], bfr[cf], acc[rf][cf], 0, 0, 0);
    __syncthreads();
  }

#pragma unroll
  for (int cf = 0; cf < 4; ++cf) {
    float bias = b2[wn + cf * 16 + l15];
#pragma unroll
    for (int rf = 0; rf < 4; ++rf) {
      size_t rbase = r0 + wm + rf * 16 + l4 * 4;
#pragma unroll
      for (int j = 0; j < 4; ++j)
        G3[(rbase + j) * 256 + wn + cf * 16 + l15] = acc[rf][cf][j] + bias;
    }
  }
}

// ---------------- counting sort of points by c3 ----------------

__global__ void k_zero(int* __restrict__ hist) {
  hist[blockIdx.x * 256 + threadIdx.x] = 0;
}

__global__ void k_hist(const int* __restrict__ coords, int* __restrict__ hist, int N) {
  int n = blockIdx.x * blockDim.x + threadIdx.x;
  if (n < N)
    atomicAdd(&hist[coord_c3(coords[2 * n], coords[2 * n + 1])], 1);
}

// 3-level parallel scan of hist[65536]
__global__ void k_scan1(const int* __restrict__ hist, int* __restrict__ scani,
                        int* __restrict__ bsum) {
  __shared__ int ps[256];
  int b = blockIdx.x, t = threadIdx.x, g = b * 256 + t;
  int h = hist[g];
  ps[t] = h;
  __syncthreads();
#pragma unroll
  for (int off = 1; off < 256; off <<= 1) {
    int v = (t >= off) ? ps[t - off] : 0;
    __syncthreads();
    ps[t] += v;
    __syncthreads();
  }
  scani[g] = ps[t];
  if (t == 255) bsum[b] = ps[255];
}

__global__ void k_scan2(const int* __restrict__ bsum, int* __restrict__ boff) {
  __shared__ int ps[256];
  int t = threadIdx.x;
  int v0 = bsum[t];
  ps[t] = v0;
  __syncthreads();
#pragma unroll
  for (int off = 1; off < 256; off <<= 1) {
    int v = (t >= off) ? ps[t - off] : 0;
    __syncthreads();
    ps[t] += v;
    __syncthreads();
  }
  boff[t] = ps[t] - v0;
}

__global__ void k_scan3(const int* __restrict__ hist, const int* __restrict__ scani,
                        const int* __restrict__ boff, int* __restrict__ start,
                        int* __restrict__ cursor) {
  int b = blockIdx.x, t = threadIdx.x, g = b * 256 + t;
  int h = hist[g];
  int ex = boff[b] + scani[g] - h;
  start[g] = ex;
  cursor[g] = ex;
  if (g == 65535) start[65536] = ex + h;
}

__global__ void k_scatter(const int* __restrict__ coords, int* __restrict__ cursor,
                          unsigned* __restrict__ sorted, int N) {
  int n = blockIdx.x * blockDim.x + threadIdx.x;
  if (n < N) {
    int x = coords[2 * n], y = coords[2 * n + 1];
    int c3 = coord_c3(x, y);
    int i3 = (y & 3) * 4 + (x & 3);
    int pos = atomicAdd(&cursor[c3], 1);
    sorted[pos] = ((unsigned)n << 4) | (unsigned)i3;
  }
}

// Sorted output via angle addition: per c3 group (16 lanes), sincos30(G3 row)
// computed once into registers; per point h = sA*tc[i3] + cA*ts[i3] (2 VALU).
__global__ void __launch_bounds__(256) k_out3(
    const float* __restrict__ G3, const float* __restrict__ TC,
    const float* __restrict__ TS, const unsigned* __restrict__ sorted,
    const int* __restrict__ start, const float* __restrict__ Wl,
    const float* __restrict__ bl, float* __restrict__ out) {
  __shared__ float tc[16 * 256];
  __shared__ float ts[16 * 256];
  int t = threadIdx.x;
#pragma unroll
  for (int i = 0; i < 4; ++i) {
    *(float4*)(tc + (t + i * 256) * 4) = *(const float4*)(TC + (t + i * 256) * 4);
    *(float4*)(ts + (t + i * 256) * 4) = *(const float4*)(TS + (t + i * 256) * 4);
  }
  __syncthreads();

  int l = t & 15;
  int c3 = blockIdx.x * 16 + (t >> 4);
  float wl[4][4][3];
#pragma unroll
  for (int j = 0; j < 4; ++j)
#pragma unroll
    for (int k = 0; k < 4; ++k) {
      int d = j * 64 + l * 4 + k;
      wl[j][k][0] = Wl[d * 3 + 0];
      wl[j][k][1] = Wl[d * 3 + 1];
      wl[j][k][2] = Wl[d * 3 + 2];
    }
  float blv0 = bl[0], blv1 = bl[1], blv2 = bl[2];

  // per-c3 sincos of the G3 row (once per bucket)
  float sA[16], cA[16];
  const float* gp = G3 + (size_t)c3 * 256 + l * 4;
#pragma unroll
  for (int j = 0; j < 4; ++j) {
    float4 g = *(const float4*)(gp + j * 64);
    float gv[4] = {g.x, g.y, g.z, g.w};
#pragma unroll
    for (int k = 0; k < 4; ++k)
      sincos30(gv[k], &sA[j * 4 + k], &cA[j * 4 + k]);
  }

  int s = start[c3], e = start[c3 + 1];
#pragma unroll 1
  for (int p = s; p < e; ++p) {
    unsigned ev = sorted[p];
    int n = (int)(ev >> 4);
    int i3 = (int)(ev & 15u);
    const float* tcp = tc + i3 * 256 + l * 4;
    const float* tsp = ts + i3 * 256 + l * 4;
    float p0 = 0.f, p1 = 0.f, p2 = 0.f;
#pragma unroll
    for (int j = 0; j < 4; ++j) {
      float4 c4 = *(const float4*)(tcp + j * 64);
      float4 s4 = *(const float4*)(tsp + j * 64);
      float cv[4] = {c4.x, c4.y, c4.z, c4.w};
      float sv[4] = {s4.x, s4.y, s4.z, s4.w};
#pragma unroll
      for (int k = 0; k < 4; ++k) {
        float h = sA[j * 4 + k] * cv[k];
        h = __builtin_fmaf(cA[j * 4 + k], sv[k], h);
        p0 = __builtin_fmaf(h, wl[j][k][0], p0);
        p1 = __builtin_fmaf(h, wl[j][k][1], p1);
        p2 = __builtin_fmaf(h, wl[j][k][2], p2);
      }
    }
#pragma unroll
    for (int off = 1; off < 16; off <<= 1) {
      p0 += __shfl_xor(p0, off);
      p1 += __shfl_xor(p1, off);
      p2 += __shfl_xor(p2, off);
    }
    if (l == 0) {
      out[n * 3 + 0] = p0 + blv0;
      out[n * 3 + 1] = p1 + blv1;
      out[n * 3 + 2] = p2 + blv2;
    }
  }
}

// -------- fallback (ws too small): exact-f32 direct, block per point --------
__global__ void k_direct(const int* __restrict__ coords, const float* __restrict__ W0,
                         const float* __restrict__ b0, const float* __restrict__ Wh,
                         const float* __restrict__ bh, const float* __restrict__ emb,
                         const float* __restrict__ modW, const float* __restrict__ Wl,
                         const float* __restrict__ bl, float* __restrict__ out) {
  __shared__ float xs[256];
  __shared__ float red[256];
  int n = blockIdx.x, d = threadIdx.x;
  int x = coords[2 * n], y = coords[2 * n + 1];
  float lvx = (float)((x >> 8) & 3), lvy = (float)((y >> 8) & 3);
  int idx[4];
  idx[0] = ((y >> 6) & 3) * 4 + ((x >> 6) & 3);
  idx[1] = ((y >> 4) & 3) * 4 + ((x >> 4) & 3);
  idx[2] = ((y >> 2) & 3) * 4 + ((x >> 2) & 3);
  idx[3] = (y & 3) * 4 + (x & 3);
  float m = 0.0f;
#pragma unroll
  for (int e = 0; e < 16; ++e)
    m = __builtin_fmaf(emb[idx[0] * 16 + e], modW[e * 256 + d], m);
  float t = fbar(lvx * W0[d]);
  t = __builtin_fmaf(lvy, W0[256 + d], t);
  t = fbar(t + b0[d]);
  float p = fbar(30.0f * m);
  float xv = fbar(t + p);
  xs[d] = sinf(fbar(30.0f * xv));
  __syncthreads();
  for (int j = 0; j < 3; ++j) {
    float acc = 0.0f;
    for (int k = 0; k < 256; ++k)
      acc = __builtin_fmaf(xs[k], Wh[j * 65536 + k * 256 + d], acc);
    float tt = fbar(acc + bh[j * 256 + d]);
    m = 0.0f;
#pragma unroll
    for (int e = 0; e < 16; ++e)
      m = __builtin_fmaf(emb[(j + 1) * 256 + idx[j + 1] * 16 + e],
                         modW[((j + 1) * 16 + e) * 256 + d], m);
    p = fbar(30.0f * m);
    xv = fbar(tt + p);
    float h = sinf(fbar(30.0f * xv));
    __syncthreads();
    xs[d] = h;
    __syncthreads();
  }
  for (int q = 0; q < 3; ++q) {
    red[d] = xs[d] * Wl[d * 3 + q];
    __syncthreads();
    for (int s = 128; s > 0; s >>= 1) {
      if (d < s) red[d] += red[d + s];
      __syncthreads();
    }
    if (d == 0) out[n * 3 + q] = red[0] + bl[q];
    __syncthreads();
  }
}

// -------------------- launch --------------------
extern "C" void kernel_launch(void* const* d_in, const int* in_sizes, int n_in,
                              void* d_out, int out_size, void* d_ws, size_t ws_size,
                              hipStream_t stream) {
  const int*   coords = (const int*)d_in[0];
  const float* W0   = (const float*)d_in[1];
  const float* b0   = (const float*)d_in[2];
  const float* Wh   = (const float*)d_in[3];
  const float* bh   = (const float*)d_in[4];
  const float* emb  = (const float*)d_in[5];
  const float* modW = (const float*)d_in[6];
  const float* Wl   = (const float*)d_in[7];
  const float* bl   = (const float*)d_in[8];
  float* out = (float*)d_out;
  const int N = in_sizes[0] / 2;

  // layout: Mf | B2T | Ah | Al | G3(overlays H1,H2) | hist | start | cursor |
  //         sorted | scani | bsum | boff | TC | TS
  const size_t OFF_MF     = 0;          //  65536
  const size_t OFF_B2T    = 65536;      //  393216
  const size_t OFF_AH     = 458752;     //  33554432
  const size_t OFF_AL     = 34013184;   //  33554432
  const size_t OFF_G3     = 67567616;   //  67108864
  const size_t OFF_H1     = 67567616;   //  262144
  const size_t OFF_H2     = 67829760;   //  4194304
  const size_t OFF_HIST   = 134676480;  //  262144
  const size_t OFF_START  = 134938624;  //  262148
  const size_t OFF_CURSOR = 135200772;  //  262144
  const size_t OFF_SORTED = 135462916;  //  1048576
  const size_t OFF_SCANI  = 136511492;  //  262144
  const size_t OFF_BSUM   = 136773636;  //  1024
  const size_t OFF_BOFF   = 136774660;  //  1024
  const size_t OFF_TC     = 136775936;  //  16384 (16B aligned)
  const size_t OFF_TS     = 136792320;  //  16384
  const size_t NEED       = 136808704;

  if (ws_size >= NEED) {
    char* ws = (char*)d_ws;
    float*          Mf     = (float*)(ws + OFF_MF);
    unsigned short* B2T    = (unsigned short*)(ws + OFF_B2T);
    unsigned short* Ahp    = (unsigned short*)(ws + OFF_AH);
    unsigned short* Alp    = (unsigned short*)(ws + OFF_AL);
    float*          G3     = (float*)(ws + OFF_G3);
    float*          H1     = (float*)(ws + OFF_H1);
    float*          H2     = (float*)(ws + OFF_H2);
    int*            hist   = (int*)(ws + OFF_HIST);
    int*            startA = (int*)(ws + OFF_START);
    int*            cursor = (int*)(ws + OFF_CURSOR);
    unsigned*       sorted = (unsigned*)(ws + OFF_SORTED);
    int*            scani  = (int*)(ws + OFF_SCANI);
    int*            bsum   = (int*)(ws + OFF_BSUM);
    int*            boff   = (int*)(ws + OFF_BOFF);
    float*          TC     = (float*)(ws + OFF_TC);
    float*          TS     = (float*)(ws + OFF_TS);

    // sort pipeline (independent of the math pipeline until k_out3)
    k_zero<<<256, 256, 0, stream>>>(hist);
    k_hist<<<1024, 256, 0, stream>>>(coords, hist, N);
    k_scan1<<<256, 256, 0, stream>>>(hist, scani, bsum);
    k_scan2<<<1, 256, 0, stream>>>(bsum, boff);
    k_scan3<<<256, 256, 0, stream>>>(hist, scani, boff, startA, cursor);
    k_scatter<<<1024, 256, 0, stream>>>(coords, cursor, sorted, N);

    k_mod<<<64, 256, 0, stream>>>(emb, modW, Mf);
    k_tab<<<16, 256, 0, stream>>>(Mf + 12288, TC, TS);
    k_splitb<<<256, 256, 0, stream>>>(Wh + 131072, B2T);
    k_h1<<<256, 256, 0, stream>>>(W0, b0, Mf, H1);
    k_h2<<<256, 256, 0, stream>>>(H1, Wh, bh, Mf + 4096, H2);
    k_h3ab<<<1024, 256, 0, stream>>>(H2, Wh + 65536, bh + 256, Mf + 8192, Ahp, Alp);
    k_gemm<<<512, 512, 0, stream>>>(Ahp, Alp, B2T, bh + 512, G3);
    k_out3<<<4096, 256, 0, stream>>>(G3, TC, TS, sorted, startA, Wl, bl, out);
  } else {
    k_direct<<<N, 256, 0, stream>>>(coords, W0, b0, Wh, bh, emb, modW, Wl, bl, out);
  }
}

// Round 8
// 168.205 us; speedup vs baseline: 1.9981x; 1.0443x over previous
//
#include <hip/hip_runtime.h>
#include <hip/hip_bf16.h>
#include <math.h>

// Modulated SIREN over 2-bit coordinate fields. Reference is a float32
// re-execution; network is chaotic (per-layer gain ~21-30x) so layers 1-2
// replicate the f32 rounding chain op-by-op (sequential fma, fbar value
// barriers, libm sinf). Layers 3-4 tolerate ~1e-3 output error -> inline
// sin30/sincos30 (double-single range reduction + Taylor).
// Layer-4 GEMM on MFMA via exact bf16 2-term split (K=768: [Ah,Ah,Al]@[Bh;Bl;Bh]).
// GEMM epilogue computes sincos30(G3) in-register and stores packed bf16
// (sA,cA) pairs -> k_out's per-bucket prep is just 16 loads + bit-unpacks.
// Output stage: counting-sort points by c3 (3-level parallel scan); per c3
// group (16 lanes) angle-addition h = sA*cos(pm) + cA*sin(pm) (2 fma/elem).

typedef float  f32x4  __attribute__((ext_vector_type(4)));
typedef int    i32x4  __attribute__((ext_vector_type(4)));
typedef __bf16 bf16x8 __attribute__((ext_vector_type(8)));

__device__ __forceinline__ float fbar(float v) {
  asm volatile("" : "+v"(v));
  return v;
}

__device__ __forceinline__ unsigned short f2bf_rne(float x) {
  unsigned u = __float_as_uint(x);
  unsigned r = (u + 0x7fffu + ((u >> 16) & 1u)) >> 16;
  return (unsigned short)r;
}

// sin(30*x), |x| <~ 200. Double-single range reduction by 30/2pi, half-period
// fold via rint, deg-11 odd Taylor, parity sign. ~1e-6 abs.
__device__ __forceinline__ float sin30(float x) {
  const float Ch = 4.774648189544678f;
  const float Cl = 1.0321218e-07f;
  float revh = x * Ch;
  fbar(revh);
  float e    = __builtin_fmaf(x, Ch, -revh);
  float revl = __builtin_fmaf(x, Cl, e);
  float k2   = __builtin_rintf(revh + revh);
  float g    = __builtin_fmaf(k2, -0.5f, revh) + revl;
  float g2 = g * g;
  float r = -15.0946f;
  r = __builtin_fmaf(r, g2, 42.0601f);
  r = __builtin_fmaf(r, g2, -76.70585f);
  r = __builtin_fmaf(r, g2, 81.6052492f);
  r = __builtin_fmaf(r, g2, -41.341702f);
  r = __builtin_fmaf(r, g2, 6.2831853f);
  float s = g * r;
  int ki = (int)k2;
  return __uint_as_float(__float_as_uint(s) ^ ((unsigned)(ki & 1) << 31));
}

// sin(30*x) AND cos(30*x): shared range reduction, odd+even Taylor polys.
__device__ __forceinline__ void sincos30(float x, float* so, float* co) {
  const float Ch = 4.774648189544678f;
  const float Cl = 1.0321218e-07f;
  float revh = x * Ch;
  fbar(revh);
  float e    = __builtin_fmaf(x, Ch, -revh);
  float revl = __builtin_fmaf(x, Cl, e);
  float k2   = __builtin_rintf(revh + revh);
  float g    = __builtin_fmaf(k2, -0.5f, revh) + revl;
  float u = g * g;
  float sr = -15.0946f;
  sr = __builtin_fmaf(sr, u, 42.0601f);
  sr = __builtin_fmaf(sr, u, -76.70585f);
  sr = __builtin_fmaf(sr, u, 81.6052492f);
  sr = __builtin_fmaf(sr, u, -41.341702f);
  sr = __builtin_fmaf(sr, u, 6.2831853f);
  float s = g * sr;
  float cr = -26.4259f;
  cr = __builtin_fmaf(cr, u, 60.2446f);
  cr = __builtin_fmaf(cr, u, -85.4568f);
  cr = __builtin_fmaf(cr, u, 64.9393940f);
  cr = __builtin_fmaf(cr, u, -19.7392088f);
  float c = __builtin_fmaf(cr, u, 1.0f);
  int ki = (int)k2;
  unsigned sgn = ((unsigned)(ki & 1)) << 31;
  *so = __uint_as_float(__float_as_uint(s) ^ sgn);
  *co = __uint_as_float(__float_as_uint(c) ^ sgn);
}

__device__ __forceinline__ int coord_c3(int x, int y) {
  int c1 = ((x >> 8) & 3) * 64 + ((y >> 8) & 3) * 16 +
           (((y >> 6) & 3) * 4 + ((x >> 6) & 3));
  int i1 = ((y >> 4) & 3) * 4 + ((x >> 4) & 3);
  int i2 = ((y >> 2) & 3) * 4 + ((x >> 2) & 3);
  return (c1 * 16 + i1) * 16 + i2;
}

// Fused prep: blocks 0-63 = Mf (modulator tables, f32 sequential fma);
// blocks 48-63 also emit TC/TS (level-3 angle tables); blocks 64-319 = B2T split.
__global__ void k_prep(const float* __restrict__ emb, const float* __restrict__ modW,
                       float* __restrict__ Mf, float* __restrict__ TC,
                       float* __restrict__ TS, const float* __restrict__ W2,
                       unsigned short* __restrict__ B2T) {
  int b = blockIdx.x, d = threadIdx.x;
  if (b < 64) {
    int j = b >> 4, i = b & 15;
    float acc = 0.0f;
#pragma unroll
    for (int e = 0; e < 16; ++e)
      acc = __builtin_fmaf(emb[j * 256 + i * 16 + e], modW[(j * 16 + e) * 256 + d], acc);
    Mf[b * 256 + d] = acc;
    if (j == 3) {
      float pm = fbar(30.0f * acc);
      float s, c;
      sincos30(pm, &s, &c);
      TC[i * 256 + d] = c;
      TS[i * 256 + d] = s;
    }
  } else {
    int col = b - 64, k = d;
    float w = W2[k * 256 + col];
    unsigned short hi = f2bf_rne(w);
    float hif = __uint_as_float((unsigned)hi << 16);
    unsigned short lo = f2bf_rne(w - hif);
    B2T[col * 768 + k] = hi;
    B2T[col * 768 + 256 + k] = lo;
    B2T[col * 768 + 512 + k] = hi;
  }
}

// Fused layers 1-3: block b (of 1024) handles c2 rows [4b,4b+4) (all same
// c1 = b>>2). Recomputes the (trivial) H1 row, h2 dot in LDS, then the h3
// body emitting the exact bf16 split Ah+Al. Numeric chains identical to the
// previous separate k_h1/k_h2/k_h3ab kernels.
__global__ void __launch_bounds__(256) k_h123(
    const float* __restrict__ W0, const float* __restrict__ b0,
    const float* __restrict__ Wh0, const float* __restrict__ bh0,
    const float* __restrict__ W1, const float* __restrict__ b1,
    const float* __restrict__ Mf,
    unsigned short* __restrict__ Ah, unsigned short* __restrict__ Al) {
  __shared__ float xs1[256];
  __shared__ float xs2[4][256];
  int b = blockIdx.x, d = threadIdx.x;
  int c1 = b >> 2;
  // ---- layer 1 (libm sinf, exact chain) ----
  float lvx = (float)((c1 >> 6) & 3), lvy = (float)((c1 >> 4) & 3);
  int i0 = c1 & 15;
  float t = fbar(lvx * W0[d]);
  t = __builtin_fmaf(lvy, W0[256 + d], t);
  t = fbar(t + b0[d]);
  float p = fbar(30.0f * Mf[i0 * 256 + d]);
  float xv = fbar(t + p);
  xs1[d] = sinf(fbar(30.0f * xv));
  __syncthreads();
  // ---- layer 2 (libm sinf, exact chain) for the block's 4 i1 ----
  float acc = 0.0f;
  for (int k = 0; k < 256; ++k)
    acc = __builtin_fmaf(xs1[k], Wh0[k * 256 + d], acc);
  float t2 = fbar(acc + bh0[d]);
#pragma unroll
  for (int r = 0; r < 4; ++r) {
    int i1 = 4 * (b & 3) + r;
    float pp = fbar(30.0f * Mf[4096 + i1 * 256 + d]);
    float x2 = fbar(t2 + pp);
    xs2[r][d] = sinf(fbar(30.0f * x2));
  }
  __syncthreads();
  // ---- layer 3 (sin30) -> bf16 split ----
  float m2[16];
#pragma unroll
  for (int i = 0; i < 16; ++i) m2[i] = fbar(30.0f * Mf[8192 + i * 256 + d]);
  float acc3[4];
#pragma unroll
  for (int r = 0; r < 4; ++r) acc3[r] = 0.0f;
  for (int k = 0; k < 256; ++k) {
    float w = W1[k * 256 + d];
#pragma unroll
    for (int r = 0; r < 4; ++r) acc3[r] = __builtin_fmaf(xs2[r][k], w, acc3[r]);
  }
  float bias = b1[d];
#pragma unroll
  for (int r = 0; r < 4; ++r) {
    float tr = fbar(acc3[r] + bias);
    int c3base = (b * 4 + r) * 16;
#pragma unroll
    for (int i = 0; i < 16; ++i) {
      float x = fbar(tr + m2[i]);
      float h = sin30(x);
      unsigned short hi = f2bf_rne(h);
      float hif = __uint_as_float((unsigned)hi << 16);
      unsigned short lo = f2bf_rne(h - hif);
      size_t o = (size_t)(c3base + i) * 256 + d;
      Ah[o] = hi;
      Al[o] = lo;
    }
  }
}

// GEMM + sincos epilogue: SC[c3][d] = pack(bf16(sin30(G3)), bf16(cos30(G3))).
__global__ void __launch_bounds__(512, 1) k_gemm(
    const unsigned short* __restrict__ Ah, const unsigned short* __restrict__ Al,
    const unsigned short* __restrict__ B2T, const float* __restrict__ b2,
    unsigned* __restrict__ SC) {
  __shared__ unsigned short As[128 * 40];
  __shared__ unsigned short Bs[256 * 40];
  const int t = threadIdx.x;
  const int lane = t & 63, wid = t >> 6;
  const int l15 = lane & 15, l4 = lane >> 4;
  const int wm = (wid >> 2) * 64;
  const int wn = (wid & 3) * 64;
  const size_t r0 = (size_t)blockIdx.x * 128;

  const int s_arow = t >> 2, s_apart = t & 3;
  const int s_bcol0 = t >> 2, s_bcol1 = 128 + (t >> 2), s_bpart = t & 3;

  f32x4 acc[4][4];
#pragma unroll
  for (int rf = 0; rf < 4; ++rf)
#pragma unroll
    for (int cf = 0; cf < 4; ++cf) acc[rf][cf] = (f32x4){0.f, 0.f, 0.f, 0.f};

  i32x4 ra, rb0, rb1;
  ra  = *(const i32x4*)(Ah + ((r0 + s_arow) << 8) + s_apart * 8);
  rb0 = *(const i32x4*)(B2T + s_bcol0 * 768 + s_bpart * 8);
  rb1 = *(const i32x4*)(B2T + s_bcol1 * 768 + s_bpart * 8);

#pragma unroll 1
  for (int c = 0; c < 24; ++c) {
    *(i32x4*)(As + s_arow * 40 + s_apart * 8) = ra;
    *(i32x4*)(Bs + s_bcol0 * 40 + s_bpart * 8) = rb0;
    *(i32x4*)(Bs + s_bcol1 * 40 + s_bpart * 8) = rb1;
    __syncthreads();
    if (c < 23) {
      int cn = c + 1;
      int kk = cn & 7;
      const unsigned short* asrc = (cn >= 16) ? Al : Ah;
      ra  = *(const i32x4*)(asrc + ((r0 + s_arow) << 8) + kk * 32 + s_apart * 8);
      rb0 = *(const i32x4*)(B2T + s_bcol0 * 768 + cn * 32 + s_bpart * 8);
      rb1 = *(const i32x4*)(B2T + s_bcol1 * 768 + cn * 32 + s_bpart * 8);
    }
    bf16x8 af[4], bfr[4];
#pragma unroll
    for (int rf = 0; rf < 4; ++rf)
      af[rf] = __builtin_bit_cast(
          bf16x8, *(const i32x4*)(As + (wm + rf * 16 + l15) * 40 + l4 * 8));
#pragma unroll
    for (int cf = 0; cf < 4; ++cf)
      bfr[cf] = __builtin_bit_cast(
          bf16x8, *(const i32x4*)(Bs + (wn + cf * 16 + l15) * 40 + l4 * 8));
#pragma unroll
    for (int rf = 0; rf < 4; ++rf)
#pragma unroll
      for (int cf = 0; cf < 4; ++cf)
        acc[rf][cf] = __builtin_amdgcn_mfma_f32_16x16x32_bf16(
            af[rf], bfr[cf], acc[rf][cf], 0, 0, 0);
    __syncthreads();
  }

#pragma unroll
  for (int cf = 0; cf < 4; ++cf) {
    float bias = b2[wn + cf * 16 + l15];
#pragma unroll
    for (int rf = 0; rf < 4; ++rf) {
      size_t rbase = r0 + wm + rf * 16 + l4 * 4;
#pragma unroll
      for (int j = 0; j < 4; ++j) {
        float g = acc[rf][cf][j] + bias;
        float s, c;
        sincos30(g, &s, &c);
        unsigned pk = ((unsigned)f2bf_rne(s) << 16) | (unsigned)f2bf_rne(c);
        SC[(rbase + j) * 256 + wn + cf * 16 + l15] = pk;
      }
    }
  }
}

// ---------------- counting sort of points by c3 ----------------

__global__ void k_zero(int* __restrict__ hist) {
  hist[blockIdx.x * 256 + threadIdx.x] = 0;
}

__global__ void k_hist(const int* __restrict__ coords, int* __restrict__ hist, int N) {
  int n = blockIdx.x * blockDim.x + threadIdx.x;
  if (n < N)
    atomicAdd(&hist[coord_c3(coords[2 * n], coords[2 * n + 1])], 1);
}

__global__ void k_scan1(const int* __restrict__ hist, int* __restrict__ scani,
                        int* __restrict__ bsum) {
  __shared__ int ps[256];
  int b = blockIdx.x, t = threadIdx.x, g = b * 256 + t;
  int h = hist[g];
  ps[t] = h;
  __syncthreads();
#pragma unroll
  for (int off = 1; off < 256; off <<= 1) {
    int v = (t >= off) ? ps[t - off] : 0;
    __syncthreads();
    ps[t] += v;
    __syncthreads();
  }
  scani[g] = ps[t];
  if (t == 255) bsum[b] = ps[255];
}

__global__ void k_scan2(const int* __restrict__ bsum, int* __restrict__ boff) {
  __shared__ int ps[256];
  int t = threadIdx.x;
  int v0 = bsum[t];
  ps[t] = v0;
  __syncthreads();
#pragma unroll
  for (int off = 1; off < 256; off <<= 1) {
    int v = (t >= off) ? ps[t - off] : 0;
    __syncthreads();
    ps[t] += v;
    __syncthreads();
  }
  boff[t] = ps[t] - v0;
}

__global__ void k_scan3(const int* __restrict__ hist, const int* __restrict__ scani,
                        const int* __restrict__ boff, int* __restrict__ start,
                        int* __restrict__ cursor) {
  int b = blockIdx.x, t = threadIdx.x, g = b * 256 + t;
  int h = hist[g];
  int ex = boff[b] + scani[g] - h;
  start[g] = ex;
  cursor[g] = ex;
  if (g == 65535) start[65536] = ex + h;
}

__global__ void k_scatter(const int* __restrict__ coords, int* __restrict__ cursor,
                          unsigned* __restrict__ sorted, int N) {
  int n = blockIdx.x * blockDim.x + threadIdx.x;
  if (n < N) {
    int x = coords[2 * n], y = coords[2 * n + 1];
    int c3 = coord_c3(x, y);
    int i3 = (y & 3) * 4 + (x & 3);
    int pos = atomicAdd(&cursor[c3], 1);
    sorted[pos] = ((unsigned)n << 4) | (unsigned)i3;
  }
}

// one point: h_d = sA_d*tc[i3,d] + cA_d*ts[i3,d]; out = h @ Wl + bl
__device__ __forceinline__ void out_point(
    unsigned ev, const float* __restrict__ tc, const float* __restrict__ ts,
    const float* sA, const float* cA, const float wl[4][4][3],
    float blv0, float blv1, float blv2, int l, float* __restrict__ out) {
  int n = (int)(ev >> 4);
  int i3 = (int)(ev & 15u);
  const float* tcp = tc + i3 * 256 + l * 4;
  const float* tsp = ts + i3 * 256 + l * 4;
  float p0 = 0.f, p1 = 0.f, p2 = 0.f;
#pragma unroll
  for (int j = 0; j < 4; ++j) {
    float4 c4 = *(const float4*)(tcp + j * 64);
    float4 s4 = *(const float4*)(tsp + j * 64);
    float cv[4] = {c4.x, c4.y, c4.z, c4.w};
    float sv[4] = {s4.x, s4.y, s4.z, s4.w};
#pragma unroll
    for (int k = 0; k < 4; ++k) {
      float h = sA[j * 4 + k] * cv[k];
      h = __builtin_fmaf(cA[j * 4 + k], sv[k], h);
      p0 = __builtin_fmaf(h, wl[j][k][0], p0);
      p1 = __builtin_fmaf(h, wl[j][k][1], p1);
      p2 = __builtin_fmaf(h, wl[j][k][2], p2);
    }
  }
#pragma unroll
  for (int off = 1; off < 16; off <<= 1) {
    p0 += __shfl_xor(p0, off);
    p1 += __shfl_xor(p1, off);
    p2 += __shfl_xor(p2, off);
  }
  if (l == 0) {
    out[n * 3 + 0] = p0 + blv0;
    out[n * 3 + 1] = p1 + blv1;
    out[n * 3 + 2] = p2 + blv2;
  }
}

// Sorted output: one 16-lane group per c3; packed bf16 (sA,cA) row unpacked
// into registers (16 loads + 32 bit-ops, no per-bucket sincos). Points
// processed in pairs for ILP.
__global__ void __launch_bounds__(256) k_out4(
    const unsigned* __restrict__ SC, const float* __restrict__ TC,
    const float* __restrict__ TS, const unsigned* __restrict__ sorted,
    const int* __restrict__ start, const float* __restrict__ Wl,
    const float* __restrict__ bl, float* __restrict__ out) {
  __shared__ float tc[16 * 256];
  __shared__ float ts[16 * 256];
  int t = threadIdx.x;
#pragma unroll
  for (int i = 0; i < 4; ++i) {
    *(float4*)(tc + (t + i * 256) * 4) = *(const float4*)(TC + (t + i * 256) * 4);
    *(float4*)(ts + (t + i * 256) * 4) = *(const float4*)(TS + (t + i * 256) * 4);
  }
  __syncthreads();

  int l = t & 15;
  int c3 = blockIdx.x * 16 + (t >> 4);
  float wl[4][4][3];
#pragma unroll
  for (int j = 0; j < 4; ++j)
#pragma unroll
    for (int k = 0; k < 4; ++k) {
      int d = j * 64 + l * 4 + k;
      wl[j][k][0] = Wl[d * 3 + 0];
      wl[j][k][1] = Wl[d * 3 + 1];
      wl[j][k][2] = Wl[d * 3 + 2];
    }
  float blv0 = bl[0], blv1 = bl[1], blv2 = bl[2];

  // unpack the bucket's (sA,cA) row
  float sA[16], cA[16];
  const unsigned* gp = SC + (size_t)c3 * 256 + l * 4;
#pragma unroll
  for (int j = 0; j < 4; ++j) {
    i32x4 u4 = *(const i32x4*)(gp + j * 64);
#pragma unroll
    for (int k = 0; k < 4; ++k) {
      unsigned u = (unsigned)u4[k];
      sA[j * 4 + k] = __uint_as_float(u & 0xffff0000u);
      cA[j * 4 + k] = __uint_as_float(u << 16);
    }
  }

  int s = start[c3], e = start[c3 + 1];
  int p = s;
  for (; p + 1 < e; p += 2) {
    unsigned ev0 = sorted[p];
    unsigned ev1 = sorted[p + 1];
    out_point(ev0, tc, ts, sA, cA, wl, blv0, blv1, blv2, l, out);
    out_point(ev1, tc, ts, sA, cA, wl, blv0, blv1, blv2, l, out);
  }
  if (p < e)
    out_point(sorted[p], tc, ts, sA, cA, wl, blv0, blv1, blv2, l, out);
}

// -------- fallback (ws too small): exact-f32 direct, block per point --------
__global__ void k_direct(const int* __restrict__ coords, const float* __restrict__ W0,
                         const float* __restrict__ b0, const float* __restrict__ Wh,
                         const float* __restrict__ bh, const float* __restrict__ emb,
                         const float* __restrict__ modW, const float* __restrict__ Wl,
                         const float* __restrict__ bl, float* __restrict__ out) {
  __shared__ float xs[256];
  __shared__ float red[256];
  int n = blockIdx.x, d = threadIdx.x;
  int x = coords[2 * n], y = coords[2 * n + 1];
  float lvx = (float)((x >> 8) & 3), lvy = (float)((y >> 8) & 3);
  int idx[4];
  idx[0] = ((y >> 6) & 3) * 4 + ((x >> 6) & 3);
  idx[1] = ((y >> 4) & 3) * 4 + ((x >> 4) & 3);
  idx[2] = ((y >> 2) & 3) * 4 + ((x >> 2) & 3);
  idx[3] = (y & 3) * 4 + (x & 3);
  float m = 0.0f;
#pragma unroll
  for (int e = 0; e < 16; ++e)
    m = __builtin_fmaf(emb[idx[0] * 16 + e], modW[e * 256 + d], m);
  float t = fbar(lvx * W0[d]);
  t = __builtin_fmaf(lvy, W0[256 + d], t);
  t = fbar(t + b0[d]);
  float p = fbar(30.0f * m);
  float xv = fbar(t + p);
  xs[d] = sinf(fbar(30.0f * xv));
  __syncthreads();
  for (int j = 0; j < 3; ++j) {
    float acc = 0.0f;
    for (int k = 0; k < 256; ++k)
      acc = __builtin_fmaf(xs[k], Wh[j * 65536 + k * 256 + d], acc);
    float tt = fbar(acc + bh[j * 256 + d]);
    m = 0.0f;
#pragma unroll
    for (int e = 0; e < 16; ++e)
      m = __builtin_fmaf(emb[(j + 1) * 256 + idx[j + 1] * 16 + e],
                         modW[((j + 1) * 16 + e) * 256 + d], m);
    p = fbar(30.0f * m);
    xv = fbar(tt + p);
    float h = sinf(fbar(30.0f * xv));
    __syncthreads();
    xs[d] = h;
    __syncthreads();
  }
  for (int q = 0; q < 3; ++q) {
    red[d] = xs[d] * Wl[d * 3 + q];
    __syncthreads();
    for (int s = 128; s > 0; s >>= 1) {
      if (d < s) red[d] += red[d + s];
      __syncthreads();
    }
    if (d == 0) out[n * 3 + q] = red[0] + bl[q];
    __syncthreads();
  }
}

// -------------------- launch --------------------
extern "C" void kernel_launch(void* const* d_in, const int* in_sizes, int n_in,
                              void* d_out, int out_size, void* d_ws, size_t ws_size,
                              hipStream_t stream) {
  const int*   coords = (const int*)d_in[0];
  const float* W0   = (const float*)d_in[1];
  const float* b0   = (const float*)d_in[2];
  const float* Wh   = (const float*)d_in[3];
  const float* bh   = (const float*)d_in[4];
  const float* emb  = (const float*)d_in[5];
  const float* modW = (const float*)d_in[6];
  const float* Wl   = (const float*)d_in[7];
  const float* bl   = (const float*)d_in[8];
  float* out = (float*)d_out;
  const int N = in_sizes[0] / 2;

  // layout: Mf | B2T | Ah | Al | SC | hist | start | cursor | sorted |
  //         scani | bsum | boff | TC | TS
  const size_t OFF_MF     = 0;          //  65536
  const size_t OFF_B2T    = 65536;      //  393216
  const size_t OFF_AH     = 458752;     //  33554432
  const size_t OFF_AL     = 34013184;   //  33554432
  const size_t OFF_SC     = 67567616;   //  67108864
  const size_t OFF_HIST   = 134676480;  //  262144
  const size_t OFF_START  = 134938624;  //  262148
  const size_t OFF_CURSOR = 135200772;  //  262144
  const size_t OFF_SORTED = 135462916;  //  1048576
  const size_t OFF_SCANI  = 136511492;  //  262144
  const size_t OFF_BSUM   = 136773636;  //  1024
  const size_t OFF_BOFF   = 136774660;  //  1024
  const size_t OFF_TC     = 136775936;  //  16384
  const size_t OFF_TS     = 136792320;  //  16384
  const size_t NEED       = 136808704;

  if (ws_size >= NEED) {
    char* ws = (char*)d_ws;
    float*          Mf     = (float*)(ws + OFF_MF);
    unsigned short* B2T    = (unsigned short*)(ws + OFF_B2T);
    unsigned short* Ahp    = (unsigned short*)(ws + OFF_AH);
    unsigned short* Alp    = (unsigned short*)(ws + OFF_AL);
    unsigned*       SC     = (unsigned*)(ws + OFF_SC);
    int*            hist   = (int*)(ws + OFF_HIST);
    int*            startA = (int*)(ws + OFF_START);
    int*            cursor = (int*)(ws + OFF_CURSOR);
    unsigned*       sorted = (unsigned*)(ws + OFF_SORTED);
    int*            scani  = (int*)(ws + OFF_SCANI);
    int*            bsum   = (int*)(ws + OFF_BSUM);
    int*            boff   = (int*)(ws + OFF_BOFF);
    float*          TC     = (float*)(ws + OFF_TC);
    float*          TS     = (float*)(ws + OFF_TS);

    // sort pipeline (independent of the math pipeline until k_out4)
    k_zero<<<256, 256, 0, stream>>>(hist);
    k_hist<<<1024, 256, 0, stream>>>(coords, hist, N);
    k_scan1<<<256, 256, 0, stream>>>(hist, scani, bsum);
    k_scan2<<<1, 256, 0, stream>>>(bsum, boff);
    k_scan3<<<256, 256, 0, stream>>>(hist, scani, boff, startA, cursor);
    k_scatter<<<1024, 256, 0, stream>>>(coords, cursor, sorted, N);

    k_prep<<<320, 256, 0, stream>>>(emb, modW, Mf, TC, TS, Wh + 131072, B2T);
    k_h123<<<1024, 256, 0, stream>>>(W0, b0, Wh, bh, Wh + 65536, bh + 256, Mf,
                                     Ahp, Alp);
    k_gemm<<<512, 512, 0, stream>>>(Ahp, Alp, B2T, bh + 512, SC);
    k_out4<<<4096, 256, 0, stream>>>(SC, TC, TS, sorted, startA, Wl, bl, out);
  } else {
    k_direct<<<N, 256, 0, stream>>>(coords, W0, b0, Wh, bh, emb, modW, Wl, bl, out);
  }
}

// Round 9
// 113.055 us; speedup vs baseline: 2.9727x; 1.4878x over previous
//
#include <hip/hip_runtime.h>
#include <hip/hip_bf16.h>
#include <math.h>

// Modulated SIREN over 2-bit coordinate fields. Reference is a float32
// re-execution; network is chaotic (per-layer gain ~21-30x) so layers 1-2
// replicate the f32 rounding chain op-by-op (sequential fma, fbar value
// barriers, libm sinf). Layers 3-4 tolerate ~1e-3 output error -> inline
// sin30/sincos30 (double-single range reduction + Taylor).
// Layer-4 GEMM on MFMA via exact bf16 2-term split (K=768: [Ah,Ah,Al]@[Bh;Bl;Bh]);
// epilogue stores packed bf16 (sin,cos) pairs SC[c3][d].
// Final layer: U[c3][i3*3+q] = sum_d sA*bf16(tc*Wl) + cA*bf16(ts*Wl) as a
// second MFMA GEMM (M=65536,K=512,N=48) -> every (c3,i3) answer; each point
// is then a 12B lookup. No sort, no atomics.

typedef float  f32x4  __attribute__((ext_vector_type(4)));
typedef int    i32x4  __attribute__((ext_vector_type(4)));
typedef __bf16 bf16x8 __attribute__((ext_vector_type(8)));

__device__ __forceinline__ float fbar(float v) {
  asm volatile("" : "+v"(v));
  return v;
}

__device__ __forceinline__ unsigned short f2bf_rne(float x) {
  unsigned u = __float_as_uint(x);
  unsigned r = (u + 0x7fffu + ((u >> 16) & 1u)) >> 16;
  return (unsigned short)r;
}

// sin(30*x), |x| <~ 200. Double-single range reduction by 30/2pi, half-period
// fold via rint, deg-11 odd Taylor, parity sign. ~1e-6 abs.
__device__ __forceinline__ float sin30(float x) {
  const float Ch = 4.774648189544678f;
  const float Cl = 1.0321218e-07f;
  float revh = x * Ch;
  fbar(revh);
  float e    = __builtin_fmaf(x, Ch, -revh);
  float revl = __builtin_fmaf(x, Cl, e);
  float k2   = __builtin_rintf(revh + revh);
  float g    = __builtin_fmaf(k2, -0.5f, revh) + revl;
  float g2 = g * g;
  float r = -15.0946f;
  r = __builtin_fmaf(r, g2, 42.0601f);
  r = __builtin_fmaf(r, g2, -76.70585f);
  r = __builtin_fmaf(r, g2, 81.6052492f);
  r = __builtin_fmaf(r, g2, -41.341702f);
  r = __builtin_fmaf(r, g2, 6.2831853f);
  float s = g * r;
  int ki = (int)k2;
  return __uint_as_float(__float_as_uint(s) ^ ((unsigned)(ki & 1) << 31));
}

// sin(30*x) AND cos(30*x): shared range reduction, odd+even Taylor polys.
__device__ __forceinline__ void sincos30(float x, float* so, float* co) {
  const float Ch = 4.774648189544678f;
  const float Cl = 1.0321218e-07f;
  float revh = x * Ch;
  fbar(revh);
  float e    = __builtin_fmaf(x, Ch, -revh);
  float revl = __builtin_fmaf(x, Cl, e);
  float k2   = __builtin_rintf(revh + revh);
  float g    = __builtin_fmaf(k2, -0.5f, revh) + revl;
  float u = g * g;
  float sr = -15.0946f;
  sr = __builtin_fmaf(sr, u, 42.0601f);
  sr = __builtin_fmaf(sr, u, -76.70585f);
  sr = __builtin_fmaf(sr, u, 81.6052492f);
  sr = __builtin_fmaf(sr, u, -41.341702f);
  sr = __builtin_fmaf(sr, u, 6.2831853f);
  float s = g * sr;
  float cr = -26.4259f;
  cr = __builtin_fmaf(cr, u, 60.2446f);
  cr = __builtin_fmaf(cr, u, -85.4568f);
  cr = __builtin_fmaf(cr, u, 64.9393940f);
  cr = __builtin_fmaf(cr, u, -19.7392088f);
  float c = __builtin_fmaf(cr, u, 1.0f);
  int ki = (int)k2;
  unsigned sgn = ((unsigned)(ki & 1)) << 31;
  *so = __uint_as_float(__float_as_uint(s) ^ sgn);
  *co = __uint_as_float(__float_as_uint(c) ^ sgn);
}

// Fused prep: blocks 0-63 = Mf (modulator tables, f32 sequential fma);
// blocks 64-319 = B2T split for the layer-4 GEMM.
__global__ void k_prep(const float* __restrict__ emb, const float* __restrict__ modW,
                       float* __restrict__ Mf, const float* __restrict__ W2,
                       unsigned short* __restrict__ B2T) {
  int b = blockIdx.x, d = threadIdx.x;
  if (b < 64) {
    int j = b >> 4, i = b & 15;
    float acc = 0.0f;
#pragma unroll
    for (int e = 0; e < 16; ++e)
      acc = __builtin_fmaf(emb[j * 256 + i * 16 + e], modW[(j * 16 + e) * 256 + d], acc);
    Mf[b * 256 + d] = acc;
  } else {
    int col = b - 64, k = d;
    float w = W2[k * 256 + col];
    unsigned short hi = f2bf_rne(w);
    float hif = __uint_as_float((unsigned)hi << 16);
    unsigned short lo = f2bf_rne(w - hif);
    B2T[col * 768 + k] = hi;
    B2T[col * 768 + 256 + k] = lo;
    B2T[col * 768 + 512 + k] = hi;
  }
}

// Final-layer B table: B2[col=i3*3+q][k], k=2d -> bf16(sin(pm)*Wl[d,q]),
// k=2d+1 -> bf16(cos(pm)*Wl[d,q]); pm = fl(30*Mf3[i3,d]). Stored as u32 pairs.
__global__ void k_prep2(const float* __restrict__ Mf3, const float* __restrict__ Wl,
                        unsigned* __restrict__ B2u) {
  int col = blockIdx.x, d = threadIdx.x;
  int i3 = col / 3, q = col - 3 * (col / 3);
  float pm = fbar(30.0f * Mf3[i3 * 256 + d]);
  float s, c;
  sincos30(pm, &s, &c);
  float w = Wl[d * 3 + q];
  unsigned ts = (unsigned)f2bf_rne(s * w);
  unsigned tc = (unsigned)f2bf_rne(c * w);
  B2u[col * 256 + d] = (tc << 16) | ts;
}

// Fused layers 1-3: block b (of 1024) handles c2 rows [4b,4b+4) (same c1).
__global__ void __launch_bounds__(256) k_h123(
    const float* __restrict__ W0, const float* __restrict__ b0,
    const float* __restrict__ Wh0, const float* __restrict__ bh0,
    const float* __restrict__ W1, const float* __restrict__ b1,
    const float* __restrict__ Mf,
    unsigned short* __restrict__ Ah, unsigned short* __restrict__ Al) {
  __shared__ float xs1[256];
  __shared__ float xs2[4][256];
  int b = blockIdx.x, d = threadIdx.x;
  int c1 = b >> 2;
  // ---- layer 1 (libm sinf, exact chain) ----
  float lvx = (float)((c1 >> 6) & 3), lvy = (float)((c1 >> 4) & 3);
  int i0 = c1 & 15;
  float t = fbar(lvx * W0[d]);
  t = __builtin_fmaf(lvy, W0[256 + d], t);
  t = fbar(t + b0[d]);
  float p = fbar(30.0f * Mf[i0 * 256 + d]);
  float xv = fbar(t + p);
  xs1[d] = sinf(fbar(30.0f * xv));
  __syncthreads();
  // ---- layer 2 (libm sinf, exact chain) for the block's 4 i1 ----
  float acc = 0.0f;
  for (int k = 0; k < 256; ++k)
    acc = __builtin_fmaf(xs1[k], Wh0[k * 256 + d], acc);
  float t2 = fbar(acc + bh0[d]);
#pragma unroll
  for (int r = 0; r < 4; ++r) {
    int i1 = 4 * (b & 3) + r;
    float pp = fbar(30.0f * Mf[4096 + i1 * 256 + d]);
    float x2 = fbar(t2 + pp);
    xs2[r][d] = sinf(fbar(30.0f * x2));
  }
  __syncthreads();
  // ---- layer 3 (sin30) -> exact bf16 split ----
  float m2[16];
#pragma unroll
  for (int i = 0; i < 16; ++i) m2[i] = fbar(30.0f * Mf[8192 + i * 256 + d]);
  float acc3[4];
#pragma unroll
  for (int r = 0; r < 4; ++r) acc3[r] = 0.0f;
  for (int k = 0; k < 256; ++k) {
    float w = W1[k * 256 + d];
#pragma unroll
    for (int r = 0; r < 4; ++r) acc3[r] = __builtin_fmaf(xs2[r][k], w, acc3[r]);
  }
  float bias = b1[d];
#pragma unroll
  for (int r = 0; r < 4; ++r) {
    float tr = fbar(acc3[r] + bias);
    int c3base = (b * 4 + r) * 16;
#pragma unroll
    for (int i = 0; i < 16; ++i) {
      float x = fbar(tr + m2[i]);
      float h = sin30(x);
      unsigned short hi = f2bf_rne(h);
      float hif = __uint_as_float((unsigned)hi << 16);
      unsigned short lo = f2bf_rne(h - hif);
      size_t o = (size_t)(c3base + i) * 256 + d;
      Ah[o] = hi;
      Al[o] = lo;
    }
  }
}

// Layer-4 GEMM + sincos epilogue: SC[c3][d] = pack(bf16(sin30(G3)), bf16(cos30(G3))).
__global__ void __launch_bounds__(512, 1) k_gemm(
    const unsigned short* __restrict__ Ah, const unsigned short* __restrict__ Al,
    const unsigned short* __restrict__ B2T, const float* __restrict__ b2,
    unsigned* __restrict__ SC) {
  __shared__ unsigned short As[128 * 40];
  __shared__ unsigned short Bs[256 * 40];
  const int t = threadIdx.x;
  const int lane = t & 63, wid = t >> 6;
  const int l15 = lane & 15, l4 = lane >> 4;
  const int wm = (wid >> 2) * 64;
  const int wn = (wid & 3) * 64;
  const size_t r0 = (size_t)blockIdx.x * 128;

  const int s_arow = t >> 2, s_apart = t & 3;
  const int s_bcol0 = t >> 2, s_bcol1 = 128 + (t >> 2), s_bpart = t & 3;

  f32x4 acc[4][4];
#pragma unroll
  for (int rf = 0; rf < 4; ++rf)
#pragma unroll
    for (int cf = 0; cf < 4; ++cf) acc[rf][cf] = (f32x4){0.f, 0.f, 0.f, 0.f};

  i32x4 ra, rb0, rb1;
  ra  = *(const i32x4*)(Ah + ((r0 + s_arow) << 8) + s_apart * 8);
  rb0 = *(const i32x4*)(B2T + s_bcol0 * 768 + s_bpart * 8);
  rb1 = *(const i32x4*)(B2T + s_bcol1 * 768 + s_bpart * 8);

#pragma unroll 1
  for (int c = 0; c < 24; ++c) {
    *(i32x4*)(As + s_arow * 40 + s_apart * 8) = ra;
    *(i32x4*)(Bs + s_bcol0 * 40 + s_bpart * 8) = rb0;
    *(i32x4*)(Bs + s_bcol1 * 40 + s_bpart * 8) = rb1;
    __syncthreads();
    if (c < 23) {
      int cn = c + 1;
      int kk = cn & 7;
      const unsigned short* asrc = (cn >= 16) ? Al : Ah;
      ra  = *(const i32x4*)(asrc + ((r0 + s_arow) << 8) + kk * 32 + s_apart * 8);
      rb0 = *(const i32x4*)(B2T + s_bcol0 * 768 + cn * 32 + s_bpart * 8);
      rb1 = *(const i32x4*)(B2T + s_bcol1 * 768 + cn * 32 + s_bpart * 8);
    }
    bf16x8 af[4], bfr[4];
#pragma unroll
    for (int rf = 0; rf < 4; ++rf)
      af[rf] = __builtin_bit_cast(
          bf16x8, *(const i32x4*)(As + (wm + rf * 16 + l15) * 40 + l4 * 8));
#pragma unroll
    for (int cf = 0; cf < 4; ++cf)
      bfr[cf] = __builtin_bit_cast(
          bf16x8, *(const i32x4*)(Bs + (wn + cf * 16 + l15) * 40 + l4 * 8));
#pragma unroll
    for (int rf = 0; rf < 4; ++rf)
#pragma unroll
      for (int cf = 0; cf < 4; ++cf)
        acc[rf][cf] = __builtin_amdgcn_mfma_f32_16x16x32_bf16(
            af[rf], bfr[cf], acc[rf][cf], 0, 0, 0);
    __syncthreads();
  }

#pragma unroll
  for (int cf = 0; cf < 4; ++cf) {
    float bias = b2[wn + cf * 16 + l15];
#pragma unroll
    for (int rf = 0; rf < 4; ++rf) {
      size_t rbase = r0 + wm + rf * 16 + l4 * 4;
#pragma unroll
      for (int j = 0; j < 4; ++j) {
        float g = acc[rf][cf][j] + bias;
        float s, c;
        sincos30(g, &s, &c);
        unsigned pk = ((unsigned)f2bf_rne(s) << 16) | (unsigned)f2bf_rne(c);
        SC[(rbase + j) * 256 + wn + cf * 16 + l15] = pk;
      }
    }
  }
}

// Final-layer GEMM: U[c3][col] = sum_k SCbf[c3][k] * B2[col][k],
// M=65536 K=512 N=48. A = SC reinterpreted as bf16 [c,s] pairs; B2 fully
// LDS-resident (48x260 u32, 2-way-pad). 512 thr = 8 waves x 16 rows.
__global__ void __launch_bounds__(512, 1) k_ugemm(
    const unsigned short* __restrict__ SCb, const unsigned* __restrict__ B2u,
    float* __restrict__ U) {
  __shared__ unsigned short As[128 * 40];
  __shared__ unsigned Bs[48 * 260];
  const int t = threadIdx.x;
  const int lane = t & 63, wid = t >> 6;
  const int l15 = lane & 15, l4 = lane >> 4;
  const int wm = wid * 16;
  const size_t r0 = (size_t)blockIdx.x * 128;

  // stage B2 (48 KB) once
#pragma unroll
  for (int i = 0; i < 24; ++i) {
    int lin = t + i * 512;           // 12288 u32 total
    int col = lin >> 8, kp = lin & 255;
    Bs[col * 260 + kp] = B2u[lin];
  }

  const int s_row = t >> 2, s_part = t & 3;
  f32x4 acc[3];
#pragma unroll
  for (int cf = 0; cf < 3; ++cf) acc[cf] = (f32x4){0.f, 0.f, 0.f, 0.f};

  i32x4 ra = *(const i32x4*)(SCb + (r0 + s_row) * 512 + s_part * 8);
#pragma unroll 1
  for (int c = 0; c < 16; ++c) {
    *(i32x4*)(As + s_row * 40 + s_part * 8) = ra;
    __syncthreads();
    if (c < 15)
      ra = *(const i32x4*)(SCb + (r0 + s_row) * 512 + (c + 1) * 32 + s_part * 8);
    bf16x8 af = __builtin_bit_cast(
        bf16x8, *(const i32x4*)(As + (wm + l15) * 40 + l4 * 8));
#pragma unroll
    for (int cf = 0; cf < 3; ++cf) {
      bf16x8 bfr = __builtin_bit_cast(
          bf16x8, *(const i32x4*)(Bs + (cf * 16 + l15) * 260 + c * 16 + l4 * 4));
      acc[cf] = __builtin_amdgcn_mfma_f32_16x16x32_bf16(af, bfr, acc[cf], 0, 0, 0);
    }
    __syncthreads();
  }

#pragma unroll
  for (int cf = 0; cf < 3; ++cf) {
    size_t rbase = r0 + wm + l4 * 4;
#pragma unroll
    for (int j = 0; j < 4; ++j)
      U[(rbase + j) * 48 + cf * 16 + l15] = acc[cf][j];
  }
}

// Per point: 12B lookup out[n] = U[c3][i3*3..+2] + bl.
__global__ void k_gather(const int* __restrict__ coords, const float* __restrict__ U,
                         const float* __restrict__ bl, float* __restrict__ out, int N) {
  int n = blockIdx.x * blockDim.x + threadIdx.x;
  if (n >= N) return;
  int x = coords[2 * n], y = coords[2 * n + 1];
  int c1 = ((x >> 8) & 3) * 64 + ((y >> 8) & 3) * 16 +
           (((y >> 6) & 3) * 4 + ((x >> 6) & 3));
  int i1 = ((y >> 4) & 3) * 4 + ((x >> 4) & 3);
  int i2 = ((y >> 2) & 3) * 4 + ((x >> 2) & 3);
  int i3 = (y & 3) * 4 + (x & 3);
  int c3 = (c1 * 16 + i1) * 16 + i2;
  const float* up = U + (size_t)c3 * 48 + i3 * 3;
  out[n * 3 + 0] = up[0] + bl[0];
  out[n * 3 + 1] = up[1] + bl[1];
  out[n * 3 + 2] = up[2] + bl[2];
}

// -------- fallback (ws too small): exact-f32 direct, block per point --------
__global__ void k_direct(const int* __restrict__ coords, const float* __restrict__ W0,
                         const float* __restrict__ b0, const float* __restrict__ Wh,
                         const float* __restrict__ bh, const float* __restrict__ emb,
                         const float* __restrict__ modW, const float* __restrict__ Wl,
                         const float* __restrict__ bl, float* __restrict__ out) {
  __shared__ float xs[256];
  __shared__ float red[256];
  int n = blockIdx.x, d = threadIdx.x;
  int x = coords[2 * n], y = coords[2 * n + 1];
  float lvx = (float)((x >> 8) & 3), lvy = (float)((y >> 8) & 3);
  int idx[4];
  idx[0] = ((y >> 6) & 3) * 4 + ((x >> 6) & 3);
  idx[1] = ((y >> 4) & 3) * 4 + ((x >> 4) & 3);
  idx[2] = ((y >> 2) & 3) * 4 + ((x >> 2) & 3);
  idx[3] = (y & 3) * 4 + (x & 3);
  float m = 0.0f;
#pragma unroll
  for (int e = 0; e < 16; ++e)
    m = __builtin_fmaf(emb[idx[0] * 16 + e], modW[e * 256 + d], m);
  float t = fbar(lvx * W0[d]);
  t = __builtin_fmaf(lvy, W0[256 + d], t);
  t = fbar(t + b0[d]);
  float p = fbar(30.0f * m);
  float xv = fbar(t + p);
  xs[d] = sinf(fbar(30.0f * xv));
  __syncthreads();
  for (int j = 0; j < 3; ++j) {
    float acc = 0.0f;
    for (int k = 0; k < 256; ++k)
      acc = __builtin_fmaf(xs[k], Wh[j * 65536 + k * 256 + d], acc);
    float tt = fbar(acc + bh[j * 256 + d]);
    m = 0.0f;
#pragma unroll
    for (int e = 0; e < 16; ++e)
      m = __builtin_fmaf(emb[(j + 1) * 256 + idx[j + 1] * 16 + e],
                         modW[((j + 1) * 16 + e) * 256 + d], m);
    p = fbar(30.0f * m);
    xv = fbar(tt + p);
    float h = sinf(fbar(30.0f * xv));
    __syncthreads();
    xs[d] = h;
    __syncthreads();
  }
  for (int q = 0; q < 3; ++q) {
    red[d] = xs[d] * Wl[d * 3 + q];
    __syncthreads();
    for (int s = 128; s > 0; s >>= 1) {
      if (d < s) red[d] += red[d + s];
      __syncthreads();
    }
    if (d == 0) out[n * 3 + q] = red[0] + bl[q];
    __syncthreads();
  }
}

// -------------------- launch --------------------
extern "C" void kernel_launch(void* const* d_in, const int* in_sizes, int n_in,
                              void* d_out, int out_size, void* d_ws, size_t ws_size,
                              hipStream_t stream) {
  const int*   coords = (const int*)d_in[0];
  const float* W0   = (const float*)d_in[1];
  const float* b0   = (const float*)d_in[2];
  const float* Wh   = (const float*)d_in[3];
  const float* bh   = (const float*)d_in[4];
  const float* emb  = (const float*)d_in[5];
  const float* modW = (const float*)d_in[6];
  const float* Wl   = (const float*)d_in[7];
  const float* bl   = (const float*)d_in[8];
  float* out = (float*)d_out;
  const int N = in_sizes[0] / 2;

  // layout: Mf | B2T | Ah | Al | SC | B2  (U overlays dead Ah)
  const size_t OFF_MF  = 0;          //  65536
  const size_t OFF_B2T = 65536;      //  393216
  const size_t OFF_AH  = 458752;     //  33554432
  const size_t OFF_AL  = 34013184;   //  33554432
  const size_t OFF_SC  = 67567616;   //  67108864
  const size_t OFF_B2  = 134676480;  //  98304 (48*512*2B)
  const size_t OFF_U   = OFF_AH;     //  12582912 (overlays Ah, dead after k_gemm)
  const size_t NEED    = 134774784;

  if (ws_size >= NEED) {
    char* ws = (char*)d_ws;
    float*          Mf  = (float*)(ws + OFF_MF);
    unsigned short* B2T = (unsigned short*)(ws + OFF_B2T);
    unsigned short* Ahp = (unsigned short*)(ws + OFF_AH);
    unsigned short* Alp = (unsigned short*)(ws + OFF_AL);
    unsigned*       SC  = (unsigned*)(ws + OFF_SC);
    unsigned*       B2u = (unsigned*)(ws + OFF_B2);
    float*          U   = (float*)(ws + OFF_U);

    k_prep<<<320, 256, 0, stream>>>(emb, modW, Mf, Wh + 131072, B2T);
    k_prep2<<<48, 256, 0, stream>>>(Mf + 12288, Wl, B2u);
    k_h123<<<1024, 256, 0, stream>>>(W0, b0, Wh, bh, Wh + 65536, bh + 256, Mf,
                                     Ahp, Alp);
    k_gemm<<<512, 512, 0, stream>>>(Ahp, Alp, B2T, bh + 512, SC);
    k_ugemm<<<512, 512, 0, stream>>>((const unsigned short*)SC, B2u, U);
    k_gather<<<(N + 255) / 256, 256, 0, stream>>>(coords, U, bl, out, N);
  } else {
    k_direct<<<N, 256, 0, stream>>>(coords, W0, b0, Wh, bh, emb, modW, Wl, bl, out);
  }
}